// Round 19
// baseline (308.023 us; speedup 1.0000x reference)
//
#include <hip/hip_runtime.h>

using bf16   = __bf16;
using bf16x8 = __attribute__((ext_vector_type(8))) bf16;
using bf16x4 = __attribute__((ext_vector_type(4))) bf16;
using f32x4  = __attribute__((ext_vector_type(4))) float;

#define DEV static __device__ __forceinline__

DEV void MFMA16(bf16x8 a, bf16x8 b, f32x4& c){
  c = __builtin_amdgcn_mfma_f32_16x16x32_bf16(a, b, c, 0, 0, 0);
}

// async global->LDS DMA, 16B per lane; lds dest is wave-uniform base + lane*16
DEV void gload16(const bf16* g, bf16* lds){
  __builtin_amdgcn_global_load_lds(
      (const __attribute__((address_space(1))) void*)g,
      (__attribute__((address_space(3))) void*)lds, 16, 0, 0);
}

// ---- vectorized transpose-cast tile: 32 rows x 128 cols ----
DEV void tcast4_dev(const float* __restrict__ in, bf16* __restrict__ out,
                    int R, int C, int bx, int by, float scale, int nscale,
                    int tid, float (*t)[129])
{
  const int c0 = bx*128, r0 = by*32;
  #pragma unroll
  for (int i = 0; i < 4; ++i){
    int row = i*8 + (tid >> 5);
    int col = (tid & 31) * 4;
    const float4 v = *(const float4*)&in[(size_t)(r0+row)*C + c0 + col];
    t[row][col+0]=v.x; t[row][col+1]=v.y; t[row][col+2]=v.z; t[row][col+3]=v.w;
  }
  __syncthreads();
  const int c = tid >> 1, rh = (tid & 1) * 16;
  const float sc = (c0 + c < nscale) ? scale : 1.f;
  bf16 tmp[16];
  #pragma unroll
  for (int j = 0; j < 16; ++j) tmp[j] = (bf16)(t[rh+j][c] * sc);
  bf16* o = out + (size_t)(c0+c)*R + r0 + rh;
  *(bf16x8*)o       = *(bf16x8*)&tmp[0];
  *(bf16x8*)(o + 8) = *(bf16x8*)&tmp[8];
}

// ---- device LayerNorm row (256 threads, row of 1024 fp32 -> bf16) ----
DEV void ln_dev(const float* __restrict__ x, const float* __restrict__ gw,
                const float* __restrict__ bw, bf16* __restrict__ y,
                int row, int tid, float (*red)[4])
{
  const float4 v = ((const float4*)(x + (size_t)row*1024))[tid];
  float s  = v.x+v.y+v.z+v.w;
  float s2 = v.x*v.x+v.y*v.y+v.z*v.z+v.w*v.w;
  #pragma unroll
  for (int off=32; off>=1; off>>=1){ s += __shfl_down(s,off); s2 += __shfl_down(s2,off); }
  const int wid = tid>>6, lane = tid&63;
  if (lane==0){ red[0][wid]=s; red[1][wid]=s2; }
  __syncthreads();
  s  = red[0][0]+red[0][1]+red[0][2]+red[0][3];
  s2 = red[1][0]+red[1][1]+red[1][2]+red[1][3];
  const float m  = s*(1.f/1024.f);
  const float rs = rsqrtf(s2*(1.f/1024.f) - m*m + 1e-5f);
  const float4 gv = ((const float4*)gw)[tid];
  const float4 bv = ((const float4*)bw)[tid];
  bf16* yr = y + (size_t)row*1024 + tid*4;
  yr[0] = (bf16)((v.x-m)*rs*gv.x + bv.x);
  yr[1] = (bf16)((v.y-m)*rs*gv.y + bv.y);
  yr[2] = (bf16)((v.z-m)*rs*gv.z + bv.z);
  yr[3] = (bf16)((v.w-m)*rs*gv.w + bv.w);
}

// ---- merged prep + LN1 ----
__global__ __launch_bounds__(256) void prep_ln(
    const float* Wqkv, bf16* wqkvT, const float* Wps, bf16* wpsT,
    const float* Wqc, bf16* wqcT, const float* Wkvc, bf16* wkvcT,
    const float* Wpc, bf16* wpcT, const float* Wf1, bf16* wf1T,
    const float* Wf2, bf16* wf2T, const float* cond, bf16* condb,
    const float* x, const float* g1, const float* b1, bf16* xn)
{
  __shared__ float t[32][129];
  __shared__ float red[2][4];
  const int bid = blockIdx.x, tid = threadIdx.x;
  if      (bid <  768) tcast4_dev(Wqkv, wqkvT, 1024, 3072, bid%24,        bid/24,        0.125f, 1024, tid, t);
  else if (bid < 1024) tcast4_dev(Wps,  wpsT,  1024, 1024, (bid-768)%8,   (bid-768)/8,   1.f, 0, tid, t);
  else if (bid < 1280) tcast4_dev(Wqc,  wqcT,  1024, 1024, (bid-1024)%8,  (bid-1024)/8,  0.125f, 1024, tid, t);
  else if (bid < 1664) tcast4_dev(Wkvc, wkvcT,  768, 2048, (bid-1280)%16, (bid-1280)/16, 1.f, 0, tid, t);
  else if (bid < 1920) tcast4_dev(Wpc,  wpcT,  1024, 1024, (bid-1664)%8,  (bid-1664)/8,  1.f, 0, tid, t);
  else if (bid < 2944) tcast4_dev(Wf1,  wf1T,  1024, 4096, (bid-1920)%32, (bid-1920)/32, 1.f, 0, tid, t);
  else if (bid < 3968) tcast4_dev(Wf2,  wf2T,  4096, 1024, (bid-2944)%8,  (bid-2944)/8,  1.f, 0, tid, t);
  else if (bid < 4084) {
    int i = (bid-3968)*256 + tid;      // float4 index over 118272/4 = 29568
    if (i < 29568) {
      const float4 v = ((const float4*)cond)[i];
      bf16 o[4] = {(bf16)v.x,(bf16)v.y,(bf16)v.z,(bf16)v.w};
      *(bf16x4*)&condb[i*4] = *(bf16x4*)o;
    }
  } else {
    ln_dev(x, g1, b1, xn, bid - 4084, tid, red);
  }
}

// ---- LayerNorm standalone (LN2/LN3) ----
__global__ __launch_bounds__(256) void ln_kernel(const float* __restrict__ x,
    const float* __restrict__ gw, const float* __restrict__ bw, bf16* __restrict__ y)
{
  __shared__ float red[2][4];
  ln_dev(x, gw, bw, y, blockIdx.x, threadIdx.x, red);
}

// ---- GEMM 256x256 PHASED (T3+T4): 8 waves, BK=64, counted-vmcnt pipeline ----
template<int MODE>
__global__ __launch_bounds__(512) void gemm256p(
    const bf16* __restrict__ A, const bf16* __restrict__ Bt,
    const float* __restrict__ bias, const float* resid,
    void* outp, int M, int N, int K)
{
  __shared__ __align__(16) bf16 As[2][256*64];
  __shared__ __align__(16) bf16 Bs[2][256*64];
  const int tid = threadIdx.x;
  const int lane = tid & 63, wid = tid >> 6;       // wid 0..7
  const int l15 = lane & 15, lh = lane >> 4;
  const int wm = wid >> 2, wn = wid & 3;           // 2 x 4 wave grid

  const int nwg = gridDim.x * gridDim.y;
  const int lin = blockIdx.y * gridDim.x + blockIdx.x;
  const int wg  = (lin & 7) * (nwg >> 3) + (lin >> 3);
  const size_t m0 = (size_t)(wg / gridDim.x) * 256;
  const size_t n0 = (size_t)(wg % gridDim.x) * 256;

  f32x4 acc[8][4];
  #pragma unroll
  for (int i=0;i<8;++i)
    #pragma unroll
    for (int j=0;j<4;++j) acc[i][j] = (f32x4){0.f,0.f,0.f,0.f};

  const int srow8 = lane >> 3;
  const int scol  = ((lane & 7) ^ srow8) * 8;
  const int NT = K >> 6;

  auto stageH = [&](int t, int j){
    if (t >= NT) return;
    const int k0 = t << 6;
    const int buf = t & 1;
    const int hl = j & 1;
    const bf16* src = (j < 2) ? A : Bt;
    const size_t base = (j < 2) ? m0 : n0;
    bf16* dst = (j < 2) ? &As[buf][0] : &Bs[buf][0];
    #pragma unroll
    for (int i = 0; i < 2; ++i) {
      int r = hl*128 + wid*16 + i*8;
      gload16(src + (base + (size_t)(r + srow8))*K + k0 + scol, dst + r*64);
    }
  };
  auto rdA = [&](int buf, int mh, int kk, bf16x8* dst){
    #pragma unroll
    for (int i=0;i<4;++i){
      int row = wm*128 + (mh*4+i)*16 + l15;
      dst[i] = *(const bf16x8*)&As[buf][row*64 + (((kk*4+lh) ^ (row&7))<<3)];
    }
  };
  auto rdB = [&](int buf, int kk, bf16x8* dst){
    #pragma unroll
    for (int n=0;n<4;++n){
      int row = wn*64 + n*16 + l15;
      dst[n] = *(const bf16x8*)&Bs[buf][row*64 + (((kk*4+lh) ^ (row&7))<<3)];
    }
  };

  stageH(0,0); stageH(0,1); stageH(0,2); stageH(0,3);
  stageH(1,0); stageH(1,1);
  if (NT > 1) asm volatile("s_waitcnt vmcnt(4)" ::: "memory");
  else        asm volatile("s_waitcnt vmcnt(0)" ::: "memory");
  __builtin_amdgcn_sched_barrier(0);
  __builtin_amdgcn_s_barrier();

  for (int t = 0; t < NT; ++t) {
    const int buf = t & 1;
    bf16x8 af0k0[4], af0k1[4], af1k0[4], af1k1[4], bfr0[4], bfr1[4];
    rdA(buf,0,0,af0k0); rdA(buf,0,1,af0k1); rdB(buf,0,bfr0);
    stageH(t+1,2);
    __builtin_amdgcn_s_barrier();
    asm volatile("s_waitcnt lgkmcnt(0)" ::: "memory");
    __builtin_amdgcn_sched_barrier(0);
    __builtin_amdgcn_s_setprio(1);
    #pragma unroll
    for (int mi=0;mi<4;++mi)
      #pragma unroll
      for (int ni=0;ni<4;++ni) MFMA16(af0k0[mi], bfr0[ni], acc[mi][ni]);
    __builtin_amdgcn_s_setprio(0);
    __builtin_amdgcn_sched_barrier(0);
    __builtin_amdgcn_s_barrier();
    rdA(buf,1,0,af1k0); rdA(buf,1,1,af1k1); rdB(buf,1,bfr1);
    stageH(t+1,3);
    __builtin_amdgcn_s_barrier();
    asm volatile("s_waitcnt lgkmcnt(0)" ::: "memory");
    __builtin_amdgcn_sched_barrier(0);
    __builtin_amdgcn_s_setprio(1);
    #pragma unroll
    for (int mi=0;mi<4;++mi)
      #pragma unroll
      for (int ni=0;ni<4;++ni) MFMA16(af1k0[mi], bfr0[ni], acc[4+mi][ni]);
    __builtin_amdgcn_s_setprio(0);
    __builtin_amdgcn_sched_barrier(0);
    __builtin_amdgcn_s_barrier();
    stageH(t+2,0);
    stageH(t+2,1);
    __builtin_amdgcn_s_setprio(1);
    #pragma unroll
    for (int mi=0;mi<4;++mi)
      #pragma unroll
      for (int ni=0;ni<4;++ni) MFMA16(af0k1[mi], bfr1[ni], acc[mi][ni]);
    #pragma unroll
    for (int mi=0;mi<4;++mi)
      #pragma unroll
      for (int ni=0;ni<4;++ni) MFMA16(af1k1[mi], bfr1[ni], acc[4+mi][ni]);
    __builtin_amdgcn_s_setprio(0);
    if (t + 2 < NT) asm volatile("s_waitcnt vmcnt(4)" ::: "memory");
    else            asm volatile("s_waitcnt vmcnt(0)" ::: "memory");
    __builtin_amdgcn_sched_barrier(0);
    __builtin_amdgcn_s_barrier();
  }

  #pragma unroll
  for (int mi=0;mi<8;++mi){
    #pragma unroll
    for (int r=0;r<4;++r){
      size_t row = m0 + wm*128 + mi*16 + 4*lh + r;
      #pragma unroll
      for (int ni=0;ni<4;++ni){
        size_t col = n0 + wn*64 + ni*16 + l15;
        float v = acc[mi][ni][r];
        if (MODE==0) ((bf16*)outp)[row*(size_t)N + col] = (bf16)v;
        else if (MODE==1) ((float*)outp)[row*(size_t)N + col] = v + bias[col] + resid[row*(size_t)N + col];
        else { v += bias[col];
               ((bf16*)outp)[row*(size_t)N + col] =
                   (bf16)(0.5f*v*(1.0f + erff(v*0.70710678f))); }
      }
    }
  }
}

// ---- merged vtsa + CA-KV GEMM (independent work, one launch) ----
// blocks [0,4096): vtsa; [4096,4128): kvca = condb[154x768] @ wkvCaT^T -> [154][2048]
__global__ __launch_bounds__(256) void vtsa_kv(
    const bf16* __restrict__ qkv, bf16* __restrict__ vt,
    const bf16* __restrict__ condb, const bf16* __restrict__ wkvCaT,
    bf16* __restrict__ kvca)
{
  __shared__ bf16 t[32][33];
  __shared__ __align__(16) bf16 As[2][128*64];
  __shared__ __align__(16) bf16 Bs[2][128*64];
  const int bid = blockIdx.x, tid = threadIdx.x;
  if (bid < 4096) {
    const int bx = bid & 63, byy = (bid >> 6) & 1, bz = bid >> 7;
    const int b = bz >> 4, h = bz & 15;
    const int s0 = bx*32, d0 = byy*32;
    const int tx = tid & 31, ty = tid >> 5;
    #pragma unroll
    for (int i = ty; i < 32; i += 8)
      t[i][tx] = qkv[(size_t)(b*2048 + s0+i)*3072 + 2048 + h*64 + d0 + tx];
    __syncthreads();
    #pragma unroll
    for (int i = ty; i < 32; i += 8)
      vt[((size_t)bz*64 + d0+i)*2048 + s0 + tx] = t[tx][i];
    return;
  }
  // ---- kvca GEMM (128x128 tile, 2-phase dbuf, M=154 N=2048 K=768) ----
  const int g = bid - 4096;
  const int M = 154, N = 2048, K = 768;
  const int lane = tid & 63, wid = tid >> 6;
  const int l15 = lane & 15, lh = lane >> 4;
  const int wm = wid >> 1, wn = wid & 1;
  const size_t m0 = (size_t)(g >> 4) * 128;
  const size_t n0 = (size_t)(g & 15) * 128;

  f32x4 acc[4][4];
  #pragma unroll
  for (int i=0;i<4;++i)
    #pragma unroll
    for (int j=0;j<4;++j) acc[i][j] = (f32x4){0.f,0.f,0.f,0.f};

  const int srow8 = lane >> 3;
  const int scol  = ((lane & 7) ^ srow8) * 8;
  const int NT = K >> 6;

  #pragma unroll
  for (int i = 0; i < 4; ++i) {
    int r = wid*32 + i*8;
    int ar = (int)m0 + r + srow8; if (ar >= M) ar = M - 1;
    gload16(condb  + (size_t)ar*K + scol,                 &As[0][r*64]);
    gload16(wkvCaT + (n0 + (size_t)(r + srow8))*K + scol, &Bs[0][r*64]);
  }
  __syncthreads();

  for (int tt = 0; tt < NT; ++tt) {
    const int cur = tt & 1;
    if (tt + 1 < NT) {
      const int k0 = (tt+1) << 6;
      #pragma unroll
      for (int i = 0; i < 4; ++i) {
        int r = wid*32 + i*8;
        int ar = (int)m0 + r + srow8; if (ar >= M) ar = M - 1;
        gload16(condb  + (size_t)ar*K + k0 + scol,                 &As[cur^1][r*64]);
        gload16(wkvCaT + (n0 + (size_t)(r + srow8))*K + k0 + scol, &Bs[cur^1][r*64]);
      }
    }
    #pragma unroll
    for (int kk = 0; kk < 2; ++kk) {
      bf16x8 af[4], bfr[4];
      #pragma unroll
      for (int i=0;i<4;++i){
        const int arow = wm*64 + i*16 + l15;
        const int brow = wn*64 + i*16 + l15;
        af[i]  = *(const bf16x8*)&As[cur][arow*64 + (((kk*4+lh) ^ (arow&7))<<3)];
        bfr[i] = *(const bf16x8*)&Bs[cur][brow*64 + (((kk*4+lh) ^ (brow&7))<<3)];
      }
      #pragma unroll
      for (int mi=0;mi<4;++mi)
        #pragma unroll
        for (int ni=0;ni<4;++ni)
          MFMA16(af[mi], bfr[ni], acc[mi][ni]);
    }
    __syncthreads();
  }

  #pragma unroll
  for (int mi=0;mi<4;++mi){
    #pragma unroll
    for (int r=0;r<4;++r){
      size_t row = m0 + wm*64 + mi*16 + 4*lh + r;
      if (row < (size_t)M) {
        #pragma unroll
        for (int ni=0;ni<4;++ni){
          size_t col = n0 + wn*64 + ni*16 + l15;
          kvca[row*(size_t)N + col] = (bf16)acc[mi][ni][r];
        }
      }
    }
  }
}

// ---- GEMM 32x128 (BK=64, 4 blocks/CU), m-major XCD decode ----
template<int MODE>
__global__ __launch_bounds__(256) void gemm32(
    const bf16* __restrict__ A, const bf16* __restrict__ Bt,
    const float* __restrict__ bias, const float* resid,
    void* outp, int M, int N, int K)
{
  __shared__ __align__(16) bf16 As[2][32*64];
  __shared__ __align__(16) bf16 Bs[2][128*64];
  const int tid = threadIdx.x;
  const int lane = tid & 63, wid = tid >> 6;
  const int l15 = lane & 15, lh = lane >> 4;

  const int nwg = gridDim.x * gridDim.y;
  const int lin = blockIdx.y * gridDim.x + blockIdx.x;
  const int wg  = (lin & 7) * (nwg >> 3) + (lin >> 3);
  const size_t m0 = (size_t)(wg / gridDim.x) * 32;
  const size_t n0 = (size_t)(wg % gridDim.x) * 128;

  f32x4 acc[2][2];
  #pragma unroll
  for (int i=0;i<2;++i)
    #pragma unroll
    for (int j=0;j<2;++j) acc[i][j] = (f32x4){0.f,0.f,0.f,0.f};

  const int srow8 = lane >> 3;
  const int scol  = ((lane & 7) ^ srow8) * 8;

  const int NT = K >> 6;

  {
    int r = wid*8;
    gload16(A + (m0 + (size_t)(r + srow8))*K + scol, &As[0][r*64]);
  }
  #pragma unroll
  for (int i = 0; i < 4; ++i) {
    int r = wid*32 + i*8;
    gload16(Bt + (n0 + (size_t)(r + srow8))*K + scol, &Bs[0][r*64]);
  }
  __syncthreads();

  for (int t = 0; t < NT; ++t) {
    const int cur = t & 1;
    if (t + 1 < NT) {
      const int k0 = (t+1) << 6;
      {
        int r = wid*8;
        gload16(A + (m0 + (size_t)(r + srow8))*K + k0 + scol, &As[cur^1][r*64]);
      }
      #pragma unroll
      for (int i = 0; i < 4; ++i) {
        int r = wid*32 + i*8;
        gload16(Bt + (n0 + (size_t)(r + srow8))*K + k0 + scol, &Bs[cur^1][r*64]);
      }
    }
    #pragma unroll
    for (int kk = 0; kk < 2; ++kk) {
      bf16x8 af[2], bfr[2];
      #pragma unroll
      for (int i=0;i<2;++i){
        const int arow = i*16 + l15;
        af[i]  = *(const bf16x8*)&As[cur][arow*64 + (((kk*4+lh) ^ (arow&7))<<3)];
      }
      #pragma unroll
      for (int n=0;n<2;++n){
        const int brow = wid*32 + n*16 + l15;
        bfr[n] = *(const bf16x8*)&Bs[cur][brow*64 + (((kk*4+lh) ^ (brow&7))<<3)];
      }
      #pragma unroll
      for (int mi=0;mi<2;++mi)
        #pragma unroll
        for (int ni=0;ni<2;++ni)
          MFMA16(af[mi], bfr[ni], acc[mi][ni]);
    }
    __syncthreads();
  }

  #pragma unroll
  for (int mi=0;mi<2;++mi){
    #pragma unroll
    for (int r=0;r<4;++r){
      size_t row = m0 + mi*16 + 4*lh + r;
      #pragma unroll
      for (int ni=0;ni<2;++ni){
        size_t col = n0 + wid*32 + ni*16 + l15;
        float v = acc[mi][ni][r];
        if (MODE==0) ((bf16*)outp)[row*(size_t)N + col] = (bf16)v;
        else if (MODE==1) ((float*)outp)[row*(size_t)N + col] = v + bias[col] + resid[row*(size_t)N + col];
        else { v += bias[col];
               ((bf16*)outp)[row*(size_t)N + col] =
                   (bf16)(0.5f*v*(1.0f + erff(v*0.70710678f))); }
      }
    }
  }
}

// ---- flash attention body (device fn): unpaired 1-tile-per-block ----
template<int CAUSAL>
DEV void flash6_dev(int bid, int tid,
    const bf16* __restrict__ qb, long q_bstride, long qstride,
    const bf16* __restrict__ kb0, long k_bstride, long k_hstride, long kstride,
    const bf16* __restrict__ vtb, long vt_bhstride, long vtstride,
    bf16* __restrict__ out, int skv)
{
  __shared__ __align__(16) bf16 Ks[2][64*64];
  __shared__ __align__(16) bf16 Vs[2][64*64];
  __shared__ __align__(16) bf16 Ps[4][16*68];
  const int w = tid >> 6, lane = tid & 63, l15 = lane & 15, lh = lane >> 4;
  const int bh   = (bid & 7) + 8*((bid >> 3) & 3);   // bh&7 == bid&7 -> XCD-resident K/V
  const int tile = 31 - (bid >> 5);                  // longest-first dispatch
  const int b = bh >> 4, h = bh & 15;
  const int q0 = tile * 64;
  const int nkb   = CAUSAL ? tile + 1 : ((skv + 63) >> 6);
  const int nfull = CAUSAL ? tile     : (skv >> 6);

  const bf16* kbase = kb0 + (size_t)b*k_bstride + (size_t)h*k_hstride;
  const bf16* vbase = vtb + (size_t)bh*vt_bhstride;
  const int sr0 = tid >> 3, sslot = tid & 7;

  const bf16* qrow = qb + (size_t)b*q_bstride + (size_t)h*64
                        + (size_t)(q0 + w*16 + l15)*qstride;
  bf16x8 qf0 = *(const bf16x8*)(qrow + 8*lh);
  bf16x8 qf1 = *(const bf16x8*)(qrow + 32 + 8*lh);

  f32x4 o[4];
  #pragma unroll
  for (int i=0;i<4;++i) o[i] = (f32x4){0.f,0.f,0.f,0.f};
  float lacc[4] = {0.f,0.f,0.f,0.f};

  bf16x8 kreg[2], vreg[2];
  #pragma unroll
  for (int i=0;i<2;++i){
    int r = sr0 + 32*i;
    kreg[i] = *(const bf16x8*)(kbase + (size_t)r*kstride + sslot*8);
    vreg[i] = *(const bf16x8*)(vbase + (size_t)r*vtstride + sslot*8);
  }

  for (int kb = 0; kb < nkb; ++kb) {
    const int buf = kb & 1;
    #pragma unroll
    for (int i=0;i<2;++i){
      int r = sr0 + 32*i;
      int ps = (sslot ^ (r & 7)) * 8;
      *(bf16x8*)&Ks[buf][r*64 + ps] = kreg[i];
      *(bf16x8*)&Vs[buf][r*64 + ps] = vreg[i];
    }
    __syncthreads();
    if (kb + 1 < nkb) {
      #pragma unroll
      for (int i=0;i<2;++i){
        int r = sr0 + 32*i;
        kreg[i] = *(const bf16x8*)(kbase + (size_t)((kb+1)*64 + r)*kstride + sslot*8);
        vreg[i] = *(const bf16x8*)(vbase + (size_t)r*vtstride + (kb+1)*64 + sslot*8);
      }
    }
    f32x4 sf[4];
    __builtin_amdgcn_s_setprio(1);
    #pragma unroll
    for (int ni = 0; ni < 4; ++ni) {
      int kr = ni*16 + l15;
      bf16x8 kf0 = *(const bf16x8*)&Ks[buf][kr*64 + (((lh  ) ^ (kr&7))<<3)];
      bf16x8 kf1 = *(const bf16x8*)&Ks[buf][kr*64 + (((lh+4) ^ (kr&7))<<3)];
      f32x4 z = (f32x4){0.f,0.f,0.f,0.f};
      MFMA16(qf0, kf0, z);
      MFMA16(qf1, kf1, z);
      sf[ni] = z;
    }
    __builtin_amdgcn_s_setprio(0);
    if (kb >= nfull) {
      #pragma unroll
      for (int ni=0;ni<4;++ni){
        int col = kb*64 + ni*16 + l15;
        #pragma unroll
        for (int r=0;r<4;++r){
          int rowg = q0 + w*16 + 4*lh + r;
          if (col >= skv || (CAUSAL && col > rowg)) sf[ni][r] = -1e30f;
        }
      }
    }
    #pragma unroll
    for (int ni=0;ni<4;++ni){
      #pragma unroll
      for (int r=0;r<4;++r){
        float p = __expf(sf[ni][r]);
        lacc[r] += p;
        Ps[w][(4*lh + r)*68 + ni*16 + l15] = (bf16)p;
      }
    }
    bf16x8 pa0 = *(const bf16x8*)&Ps[w][l15*68 + 8*lh];
    bf16x8 pa1 = *(const bf16x8*)&Ps[w][l15*68 + 32 + 8*lh];
    __builtin_amdgcn_s_setprio(1);
    #pragma unroll
    for (int nd=0;nd<4;++nd){
      int vr = nd*16 + l15;
      bf16x8 vf0 = *(const bf16x8*)&Vs[buf][vr*64 + (((lh  ) ^ (vr&7))<<3)];
      bf16x8 vf1 = *(const bf16x8*)&Vs[buf][vr*64 + (((lh+4) ^ (vr&7))<<3)];
      MFMA16(pa0, vf0, o[nd]);
      MFMA16(pa1, vf1, o[nd]);
    }
    __builtin_amdgcn_s_setprio(0);
  }
  float lr[4];
  #pragma unroll
  for (int r=0;r<4;++r) lr[r] = lacc[r];
  #pragma unroll
  for (int off=1; off<16; off<<=1)
    #pragma unroll
    for (int r=0;r<4;++r) lr[r] += __shfl_xor(lr[r], off);
  #pragma unroll
  for (int nd=0;nd<4;++nd)
    #pragma unroll
    for (int r=0;r<4;++r){
      int rowg = q0 + w*16 + 4*lh + r;
      out[(size_t)(b*2048 + rowg)*1024 + h*64 + nd*16 + l15] =
          (bf16)(o[nd][r] / lr[r]);
    }
}

// ---- SA flash + kvca_re fused (blocks [0,1024) flash, [1024,2048) re) ----
__global__ __launch_bounds__(256) void flash6sa(
    const bf16* __restrict__ qb, long q_bstride, long qstride,
    const bf16* __restrict__ kb0, long k_bstride, long k_hstride, long kstride,
    const bf16* __restrict__ vtb, long vt_bhstride, long vtstride,
    bf16* __restrict__ out, int skv,
    const bf16* __restrict__ kvca, bf16* __restrict__ kpad, bf16* __restrict__ vtca)
{
  if (blockIdx.x >= 1024) {
    int idx = (blockIdx.x - 1024)*256 + threadIdx.x;   // over 262144
    int d = idx & 63, s = (idx>>6) & 127, h = (idx>>13) & 15, b = idx>>17;
    bf16 kv = (bf16)0.f, vv = (bf16)0.f;
    if (s < 77) {
      kv = kvca[(size_t)(b*77+s)*2048 + h*64 + d];
      vv = kvca[(size_t)(b*77+s)*2048 + 1024 + h*64 + d];
    }
    kpad[idx] = kv;                                   // [b][h][s][d]
    vtca[(((size_t)(b*16+h)*64 + d)<<7) + s] = vv;    // [b][h][d][s], stride 128
    return;
  }
  flash6_dev<1>(blockIdx.x, threadIdx.x, qb, q_bstride, qstride,
                kb0, k_bstride, k_hstride, kstride,
                vtb, vt_bhstride, vtstride, out, skv);
}

// ---- CA flash standalone ----
template<int CAUSAL>
__global__ __launch_bounds__(256) void flash6(
    const bf16* __restrict__ qb, long q_bstride, long qstride,
    const bf16* __restrict__ kb0, long k_bstride, long k_hstride, long kstride,
    const bf16* __restrict__ vtb, long vt_bhstride, long vtstride,
    bf16* __restrict__ out, int skv)
{
  flash6_dev<CAUSAL>(blockIdx.x, threadIdx.x, qb, q_bstride, qstride,
                     kb0, k_bstride, k_hstride, kstride,
                     vtb, vt_bhstride, vtstride, out, skv);
}

// ---- host ----
struct Bump { char* base; size_t off;
  void* get(size_t bytes){ void* p = base + off; off += (bytes + 255) & ~(size_t)255; return p; } };

extern "C" void kernel_launch(void* const* d_in, const int* in_sizes, int n_in,
                              void* d_out, int out_size, void* d_ws, size_t ws_size,
                              hipStream_t stream)
{
  const float* x        = (const float*)d_in[0];
  const float* cond     = (const float*)d_in[1];
  const float* Wqkv     = (const float*)d_in[2];
  const float* Wproj_sa = (const float*)d_in[3];
  const float* bproj_sa = (const float*)d_in[4];
  const float* g1       = (const float*)d_in[5];
  const float* b1       = (const float*)d_in[6];
  const float* Wq_ca    = (const float*)d_in[7];
  const float* Wkv_ca   = (const float*)d_in[8];
  const float* Wproj_ca = (const float*)d_in[9];
  const float* bproj_ca = (const float*)d_in[10];
  const float* g2       = (const float*)d_in[11];
  const float* b2       = (const float*)d_in[12];
  const float* Wff1     = (const float*)d_in[13];
  const float* bff1     = (const float*)d_in[14];
  const float* Wff2     = (const float*)d_in[15];
  const float* bff2     = (const float*)d_in[16];
  const float* g3       = (const float*)d_in[17];
  const float* b3       = (const float*)d_in[18];

  Bump bump{(char*)d_ws, 0};
  bf16* wqkvT    = (bf16*)bump.get((size_t)3072*1024*2);
  bf16* wprojSaT = (bf16*)bump.get((size_t)1024*1024*2);
  bf16* wqCaT    = (bf16*)bump.get((size_t)1024*1024*2);
  bf16* wkvCaT   = (bf16*)bump.get((size_t)2048*768*2);
  bf16* wprojCaT = (bf16*)bump.get((size_t)1024*1024*2);
  bf16* wff1T    = (bf16*)bump.get((size_t)4096*1024*2);
  bf16* wff2T    = (bf16*)bump.get((size_t)1024*4096*2);
  bf16* condb    = (bf16*)bump.get((size_t)154*768*2);
  bf16* xn       = (bf16*)bump.get((size_t)4096*1024*2);
  bf16* qkv      = (bf16*)bump.get((size_t)4096*3072*2);   // 25165824 B
  bf16* vt_sa    = (bf16*)bump.get((size_t)2*16*64*2048*2);//  8388608 B (follows qkv)
  bf16* attn     = (bf16*)bump.get((size_t)4096*1024*2);
  bf16* kvca     = (bf16*)bump.get((size_t)154*2048*2);
  bf16* kpad     = (bf16*)bump.get((size_t)2*16*128*64*2);
  bf16* vtca     = (bf16*)bump.get((size_t)2*16*64*128*2);
  bf16* h1   = qkv;             // FF hidden: qkv+vt_sa dead by FF1
  bf16* qca  = vt_sa;           // CA query: vt_sa dead after SA flash
  float* x1  = (float*)d_out;   // residual stream lives in d_out

  // weight prep + LN1 fused
  prep_ln<<<dim3(8180), 256, 0, stream>>>(
      Wqkv, wqkvT, Wproj_sa, wprojSaT, Wq_ca, wqCaT, Wkv_ca, wkvCaT,
      Wproj_ca, wprojCaT, Wff1, wff1T, Wff2, wff2T, cond, condb,
      x, g1, b1, xn);

  // self-attention (vtsa + CA-KV GEMM fused; SA flash + kvca_re fused)
  gemm256p<0><<<dim3(12,16), 512, 0, stream>>>(xn, wqkvT, nullptr, nullptr, qkv, 4096, 3072, 1024);
  vtsa_kv<<<dim3(4128), 256, 0, stream>>>(qkv, vt_sa, condb, wkvCaT, kvca);
  flash6sa<<<dim3(2048), 256, 0, stream>>>(
      qkv,        (long)2048*3072, 3072,
      qkv + 1024, (long)2048*3072, 64, 3072,
      vt_sa,      (long)64*2048, 2048,
      attn, 2048,
      kvca, kpad, vtca);
  gemm32<1><<<dim3(8,128), 256, 0, stream>>>(attn, wprojSaT, bproj_sa, x, x1, 4096, 1024, 1024);

  // cross-attention
  ln_kernel<<<dim3(4096), 256, 0, stream>>>(x1, g2, b2, xn);
  gemm32<0><<<dim3(8,128), 256, 0, stream>>>(xn, wqCaT, nullptr, nullptr, qca, 4096, 1024, 1024);
  flash6<0><<<dim3(1024), 256, 0, stream>>>(
      qca,  (long)2048*1024, 1024,
      kpad, (long)16*128*64, (long)128*64, 64,
      vtca, (long)64*128, 128,
      attn, 77);
  gemm32<1><<<dim3(8,128), 256, 0, stream>>>(attn, wprojCaT, bproj_ca, x1, x1, 4096, 1024, 1024);

  // FFN
  ln_kernel<<<dim3(4096), 256, 0, stream>>>(x1, g3, b3, xn);
  gemm256p<2><<<dim3(16,16), 512, 0, stream>>>(xn, wff1T, bff1, nullptr, h1, 4096, 4096, 1024);
  gemm32<1><<<dim3(8,128), 256, 0, stream>>>(h1, wff2T, bff2, x1, d_out, 4096, 1024, 4096);

  (void)in_sizes; (void)n_in; (void)out_size; (void)ws_size;
}

// Round 20
// 302.703 us; speedup vs baseline: 1.0176x; 1.0176x over previous
//
#include <hip/hip_runtime.h>

using bf16   = __bf16;
using bf16x8 = __attribute__((ext_vector_type(8))) bf16;
using bf16x4 = __attribute__((ext_vector_type(4))) bf16;
using f32x4  = __attribute__((ext_vector_type(4))) float;

#define DEV static __device__ __forceinline__

DEV void MFMA16(bf16x8 a, bf16x8 b, f32x4& c){
  c = __builtin_amdgcn_mfma_f32_16x16x32_bf16(a, b, c, 0, 0, 0);
}

// async global->LDS DMA, 16B per lane; lds dest is wave-uniform base + lane*16
DEV void gload16(const bf16* g, bf16* lds){
  __builtin_amdgcn_global_load_lds(
      (const __attribute__((address_space(1))) void*)g,
      (__attribute__((address_space(3))) void*)lds, 16, 0, 0);
}

// ---- vectorized transpose-cast tile: 32 rows x 128 cols of in[R?][C],
// out[c][r] = bf16(in[r][c] * (c<nscale ? scale:1)). float4 loads, bf16x8 stores.
DEV void tcast4_dev(const float* __restrict__ in, bf16* __restrict__ out,
                    int R, int C, int bx, int by, float scale, int nscale,
                    int tid, float (*t)[129])
{
  const int c0 = bx*128, r0 = by*32;
  #pragma unroll
  for (int i = 0; i < 4; ++i){
    int row = i*8 + (tid >> 5);
    int col = (tid & 31) * 4;
    const float4 v = *(const float4*)&in[(size_t)(r0+row)*C + c0 + col];
    t[row][col+0]=v.x; t[row][col+1]=v.y; t[row][col+2]=v.z; t[row][col+3]=v.w;
  }
  __syncthreads();
  const int c = tid >> 1, rh = (tid & 1) * 16;
  const float sc = (c0 + c < nscale) ? scale : 1.f;
  bf16 tmp[16];
  #pragma unroll
  for (int j = 0; j < 16; ++j) tmp[j] = (bf16)(t[rh+j][c] * sc);
  bf16* o = out + (size_t)(c0+c)*R + r0 + rh;
  *(bf16x8*)o       = *(bf16x8*)&tmp[0];
  *(bf16x8*)(o + 8) = *(bf16x8*)&tmp[8];
}

// ---- device LayerNorm row (256 threads, row of 1024 fp32 -> bf16) ----
DEV void ln_dev(const float* __restrict__ x, const float* __restrict__ gw,
                const float* __restrict__ bw, bf16* __restrict__ y,
                int row, int tid, float (*red)[4])
{
  const float4 v = ((const float4*)(x + (size_t)row*1024))[tid];
  float s  = v.x+v.y+v.z+v.w;
  float s2 = v.x*v.x+v.y*v.y+v.z*v.z+v.w*v.w;
  #pragma unroll
  for (int off=32; off>=1; off>>=1){ s += __shfl_down(s,off); s2 += __shfl_down(s2,off); }
  const int wid = tid>>6, lane = tid&63;
  if (lane==0){ red[0][wid]=s; red[1][wid]=s2; }
  __syncthreads();
  s  = red[0][0]+red[0][1]+red[0][2]+red[0][3];
  s2 = red[1][0]+red[1][1]+red[1][2]+red[1][3];
  const float m  = s*(1.f/1024.f);
  const float rs = rsqrtf(s2*(1.f/1024.f) - m*m + 1e-5f);
  const float4 gv = ((const float4*)gw)[tid];
  const float4 bv = ((const float4*)bw)[tid];
  bf16* yr = y + (size_t)row*1024 + tid*4;
  yr[0] = (bf16)((v.x-m)*rs*gv.x + bv.x);
  yr[1] = (bf16)((v.y-m)*rs*gv.y + bv.y);
  yr[2] = (bf16)((v.z-m)*rs*gv.z + bv.z);
  yr[3] = (bf16)((v.w-m)*rs*gv.w + bv.w);
}

// ---- merged prep + LN1 (independent work, one launch -> concurrent) ----
// blocks: [0,768) Wqkv | [768,1024) Wps | [1024,1280) Wqc | [1280,1664) Wkvc |
// [1664,1920) Wpc | [1920,2944) Wf1 | [2944,3968) Wf2 | [3968,4084) cond |
// [4084,8180) LN1 rows
__global__ __launch_bounds__(256) void prep_ln(
    const float* Wqkv, bf16* wqkvT, const float* Wps, bf16* wpsT,
    const float* Wqc, bf16* wqcT, const float* Wkvc, bf16* wkvcT,
    const float* Wpc, bf16* wpcT, const float* Wf1, bf16* wf1T,
    const float* Wf2, bf16* wf2T, const float* cond, bf16* condb,
    const float* x, const float* g1, const float* b1, bf16* xn)
{
  __shared__ float t[32][129];
  __shared__ float red[2][4];
  const int bid = blockIdx.x, tid = threadIdx.x;
  if      (bid <  768) tcast4_dev(Wqkv, wqkvT, 1024, 3072, bid%24,        bid/24,        0.125f, 1024, tid, t);
  else if (bid < 1024) tcast4_dev(Wps,  wpsT,  1024, 1024, (bid-768)%8,   (bid-768)/8,   1.f, 0, tid, t);
  else if (bid < 1280) tcast4_dev(Wqc,  wqcT,  1024, 1024, (bid-1024)%8,  (bid-1024)/8,  0.125f, 1024, tid, t);
  else if (bid < 1664) tcast4_dev(Wkvc, wkvcT,  768, 2048, (bid-1280)%16, (bid-1280)/16, 1.f, 0, tid, t);
  else if (bid < 1920) tcast4_dev(Wpc,  wpcT,  1024, 1024, (bid-1664)%8,  (bid-1664)/8,  1.f, 0, tid, t);
  else if (bid < 2944) tcast4_dev(Wf1,  wf1T,  1024, 4096, (bid-1920)%32, (bid-1920)/32, 1.f, 0, tid, t);
  else if (bid < 3968) tcast4_dev(Wf2,  wf2T,  4096, 1024, (bid-2944)%8,  (bid-2944)/8,  1.f, 0, tid, t);
  else if (bid < 4084) {
    int i = (bid-3968)*256 + tid;      // float4 index over 118272/4 = 29568
    if (i < 29568) {
      const float4 v = ((const float4*)cond)[i];
      bf16 o[4] = {(bf16)v.x,(bf16)v.y,(bf16)v.z,(bf16)v.w};
      *(bf16x4*)&condb[i*4] = *(bf16x4*)o;
    }
  } else {
    ln_dev(x, g1, b1, xn, bid - 4084, tid, red);
  }
}

// ---- LayerNorm standalone (for LN2/LN3) ----
__global__ __launch_bounds__(256) void ln_kernel(const float* __restrict__ x,
    const float* __restrict__ gw, const float* __restrict__ bw, bf16* __restrict__ y)
{
  __shared__ float red[2][4];
  ln_dev(x, gw, bw, y, blockIdx.x, threadIdx.x, red);
}

// ---- GEMM 256x256 PHASED (T3+T4): 8 waves, BK=64, counted-vmcnt pipeline ----
template<int MODE>
__global__ __launch_bounds__(512) void gemm256p(
    const bf16* __restrict__ A, const bf16* __restrict__ Bt,
    const float* __restrict__ bias, const float* resid,
    void* outp, int M, int N, int K)
{
  __shared__ __align__(16) bf16 As[2][256*64];
  __shared__ __align__(16) bf16 Bs[2][256*64];
  const int tid = threadIdx.x;
  const int lane = tid & 63, wid = tid >> 6;       // wid 0..7
  const int l15 = lane & 15, lh = lane >> 4;
  const int wm = wid >> 2, wn = wid & 3;           // 2 x 4 wave grid

  const int nwg = gridDim.x * gridDim.y;
  const int lin = blockIdx.y * gridDim.x + blockIdx.x;
  const int wg  = (lin & 7) * (nwg >> 3) + (lin >> 3);
  const size_t m0 = (size_t)(wg / gridDim.x) * 256;
  const size_t n0 = (size_t)(wg % gridDim.x) * 256;

  f32x4 acc[8][4];
  #pragma unroll
  for (int i=0;i<8;++i)
    #pragma unroll
    for (int j=0;j<4;++j) acc[i][j] = (f32x4){0.f,0.f,0.f,0.f};

  const int srow8 = lane >> 3;
  const int scol  = ((lane & 7) ^ srow8) * 8;
  const int NT = K >> 6;

  auto stageH = [&](int t, int j){
    if (t >= NT) return;
    const int k0 = t << 6;
    const int buf = t & 1;
    const int hl = j & 1;
    const bf16* src = (j < 2) ? A : Bt;
    const size_t base = (j < 2) ? m0 : n0;
    bf16* dst = (j < 2) ? &As[buf][0] : &Bs[buf][0];
    #pragma unroll
    for (int i = 0; i < 2; ++i) {
      int r = hl*128 + wid*16 + i*8;
      gload16(src + (base + (size_t)(r + srow8))*K + k0 + scol, dst + r*64);
    }
  };
  auto rdA = [&](int buf, int mh, int kk, bf16x8* dst){
    #pragma unroll
    for (int i=0;i<4;++i){
      int row = wm*128 + (mh*4+i)*16 + l15;
      dst[i] = *(const bf16x8*)&As[buf][row*64 + (((kk*4+lh) ^ (row&7))<<3)];
    }
  };
  auto rdB = [&](int buf, int kk, bf16x8* dst){
    #pragma unroll
    for (int n=0;n<4;++n){
      int row = wn*64 + n*16 + l15;
      dst[n] = *(const bf16x8*)&Bs[buf][row*64 + (((kk*4+lh) ^ (row&7))<<3)];
    }
  };

  stageH(0,0); stageH(0,1); stageH(0,2); stageH(0,3);
  stageH(1,0); stageH(1,1);
  if (NT > 1) asm volatile("s_waitcnt vmcnt(4)" ::: "memory");
  else        asm volatile("s_waitcnt vmcnt(0)" ::: "memory");
  __builtin_amdgcn_sched_barrier(0);
  __builtin_amdgcn_s_barrier();

  for (int t = 0; t < NT; ++t) {
    const int buf = t & 1;
    bf16x8 af0k0[4], af0k1[4], af1k0[4], af1k1[4], bfr0[4], bfr1[4];
    rdA(buf,0,0,af0k0); rdA(buf,0,1,af0k1); rdB(buf,0,bfr0);
    stageH(t+1,2);
    __builtin_amdgcn_s_barrier();
    asm volatile("s_waitcnt lgkmcnt(0)" ::: "memory");
    __builtin_amdgcn_sched_barrier(0);
    __builtin_amdgcn_s_setprio(1);
    #pragma unroll
    for (int mi=0;mi<4;++mi)
      #pragma unroll
      for (int ni=0;ni<4;++ni) MFMA16(af0k0[mi], bfr0[ni], acc[mi][ni]);
    __builtin_amdgcn_s_setprio(0);
    __builtin_amdgcn_sched_barrier(0);
    __builtin_amdgcn_s_barrier();
    rdA(buf,1,0,af1k0); rdA(buf,1,1,af1k1); rdB(buf,1,bfr1);
    stageH(t+1,3);
    __builtin_amdgcn_s_barrier();
    asm volatile("s_waitcnt lgkmcnt(0)" ::: "memory");
    __builtin_amdgcn_sched_barrier(0);
    __builtin_amdgcn_s_setprio(1);
    #pragma unroll
    for (int mi=0;mi<4;++mi)
      #pragma unroll
      for (int ni=0;ni<4;++ni) MFMA16(af1k0[mi], bfr0[ni], acc[4+mi][ni]);
    __builtin_amdgcn_s_setprio(0);
    __builtin_amdgcn_sched_barrier(0);
    __builtin_amdgcn_s_barrier();
    stageH(t+2,0);
    stageH(t+2,1);
    __builtin_amdgcn_s_setprio(1);
    #pragma unroll
    for (int mi=0;mi<4;++mi)
      #pragma unroll
      for (int ni=0;ni<4;++ni) MFMA16(af0k1[mi], bfr1[ni], acc[mi][ni]);
    #pragma unroll
    for (int mi=0;mi<4;++mi)
      #pragma unroll
      for (int ni=0;ni<4;++ni) MFMA16(af1k1[mi], bfr1[ni], acc[4+mi][ni]);
    __builtin_amdgcn_s_setprio(0);
    if (t + 2 < NT) asm volatile("s_waitcnt vmcnt(4)" ::: "memory");
    else            asm volatile("s_waitcnt vmcnt(0)" ::: "memory");
    __builtin_amdgcn_sched_barrier(0);
    __builtin_amdgcn_s_barrier();
  }

  #pragma unroll
  for (int mi=0;mi<8;++mi){
    #pragma unroll
    for (int r=0;r<4;++r){
      size_t row = m0 + wm*128 + mi*16 + 4*lh + r;
      #pragma unroll
      for (int ni=0;ni<4;++ni){
        size_t col = n0 + wn*64 + ni*16 + l15;
        float v = acc[mi][ni][r];
        if (MODE==0) ((bf16*)outp)[row*(size_t)N + col] = (bf16)v;
        else if (MODE==1) ((float*)outp)[row*(size_t)N + col] = v + bias[col] + resid[row*(size_t)N + col];
        else { v += bias[col];
               ((bf16*)outp)[row*(size_t)N + col] =
                   (bf16)(0.5f*v*(1.0f + erff(v*0.70710678f))); }
      }
    }
  }
}

// ---- GEMM 128x128: BK=64, 2-phase dbuf (small/odd shapes: CA KV) ----
template<int MODE>
__global__ __launch_bounds__(256) void gemm_bt(
    const bf16* __restrict__ A, const bf16* __restrict__ Bt,
    const float* __restrict__ bias, const float* resid,
    void* outp, int M, int N, int K)
{
  __shared__ __align__(16) bf16 As[2][128*64];
  __shared__ __align__(16) bf16 Bs[2][128*64];
  const int tid = threadIdx.x;
  const int lane = tid & 63, wid = tid >> 6;
  const int l15 = lane & 15, lh = lane >> 4;
  const int wm = wid >> 1, wn = wid & 1;

  const int nwg = gridDim.x * gridDim.y;
  const int lin = blockIdx.y * gridDim.x + blockIdx.x;
  const int wg  = (lin & 7) * (nwg >> 3) + (lin >> 3);
  const size_t m0 = (size_t)(wg / gridDim.x) * 128;
  const size_t n0 = (size_t)(wg % gridDim.x) * 128;

  f32x4 acc[4][4];
  #pragma unroll
  for (int i=0;i<4;++i)
    #pragma unroll
    for (int j=0;j<4;++j) acc[i][j] = (f32x4){0.f,0.f,0.f,0.f};

  const int srow8 = lane >> 3;
  const int scol  = ((lane & 7) ^ srow8) * 8;

  const int NT = K >> 6;

  #pragma unroll
  for (int i = 0; i < 4; ++i) {
    int r = wid*32 + i*8;
    int ar = (int)m0 + r + srow8; if (ar >= M) ar = M - 1;
    gload16(A  + (size_t)ar*K + scol,                 &As[0][r*64]);
    gload16(Bt + (n0 + (size_t)(r + srow8))*K + scol, &Bs[0][r*64]);
  }
  __syncthreads();

  for (int t = 0; t < NT; ++t) {
    const int cur = t & 1;
    if (t + 1 < NT) {
      const int k0 = (t+1) << 6;
      #pragma unroll
      for (int i = 0; i < 4; ++i) {
        int r = wid*32 + i*8;
        int ar = (int)m0 + r + srow8; if (ar >= M) ar = M - 1;
        gload16(A  + (size_t)ar*K + k0 + scol,                 &As[cur^1][r*64]);
        gload16(Bt + (n0 + (size_t)(r + srow8))*K + k0 + scol, &Bs[cur^1][r*64]);
      }
    }
    #pragma unroll
    for (int kk = 0; kk < 2; ++kk) {
      bf16x8 af[4], bfr[4];
      #pragma unroll
      for (int i=0;i<4;++i){
        const int arow = wm*64 + i*16 + l15;
        const int brow = wn*64 + i*16 + l15;
        af[i]  = *(const bf16x8*)&As[cur][arow*64 + (((kk*4+lh) ^ (arow&7))<<3)];
        bfr[i] = *(const bf16x8*)&Bs[cur][brow*64 + (((kk*4+lh) ^ (brow&7))<<3)];
      }
      #pragma unroll
      for (int mi=0;mi<4;++mi)
        #pragma unroll
        for (int ni=0;ni<4;++ni)
          MFMA16(af[mi], bfr[ni], acc[mi][ni]);
    }
    __syncthreads();
  }

  #pragma unroll
  for (int mi=0;mi<4;++mi){
    #pragma unroll
    for (int r=0;r<4;++r){
      size_t row = m0 + wm*64 + mi*16 + 4*lh + r;
      if (row < (size_t)M) {
        #pragma unroll
        for (int ni=0;ni<4;++ni){
          size_t col = n0 + wn*64 + ni*16 + l15;
          float v = acc[mi][ni][r];
          if (MODE==0) ((bf16*)outp)[row*(size_t)N + col] = (bf16)v;
          else if (MODE==1) ((float*)outp)[row*(size_t)N + col] = v + bias[col] + resid[row*(size_t)N + col];
          else { v += bias[col];
                 ((bf16*)outp)[row*(size_t)N + col] =
                     (bf16)(0.5f*v*(1.0f + erff(v*0.70710678f))); }
        }
      }
    }
  }
}

// ---- GEMM 32x128 (BK=64, 4 blocks/CU), m-major XCD decode ----
template<int MODE>
__global__ __launch_bounds__(256) void gemm32(
    const bf16* __restrict__ A, const bf16* __restrict__ Bt,
    const float* __restrict__ bias, const float* resid,
    void* outp, int M, int N, int K)
{
  __shared__ __align__(16) bf16 As[2][32*64];
  __shared__ __align__(16) bf16 Bs[2][128*64];
  const int tid = threadIdx.x;
  const int lane = tid & 63, wid = tid >> 6;
  const int l15 = lane & 15, lh = lane >> 4;

  const int nwg = gridDim.x * gridDim.y;
  const int lin = blockIdx.y * gridDim.x + blockIdx.x;
  const int wg  = (lin & 7) * (nwg >> 3) + (lin >> 3);
  const size_t m0 = (size_t)(wg / gridDim.x) * 32;
  const size_t n0 = (size_t)(wg % gridDim.x) * 128;

  f32x4 acc[2][2];
  #pragma unroll
  for (int i=0;i<2;++i)
    #pragma unroll
    for (int j=0;j<2;++j) acc[i][j] = (f32x4){0.f,0.f,0.f,0.f};

  const int srow8 = lane >> 3;
  const int scol  = ((lane & 7) ^ srow8) * 8;

  const int NT = K >> 6;

  {
    int r = wid*8;
    gload16(A + (m0 + (size_t)(r + srow8))*K + scol, &As[0][r*64]);
  }
  #pragma unroll
  for (int i = 0; i < 4; ++i) {
    int r = wid*32 + i*8;
    gload16(Bt + (n0 + (size_t)(r + srow8))*K + scol, &Bs[0][r*64]);
  }
  __syncthreads();

  for (int t = 0; t < NT; ++t) {
    const int cur = t & 1;
    if (t + 1 < NT) {
      const int k0 = (t+1) << 6;
      {
        int r = wid*8;
        gload16(A + (m0 + (size_t)(r + srow8))*K + k0 + scol, &As[cur^1][r*64]);
      }
      #pragma unroll
      for (int i = 0; i < 4; ++i) {
        int r = wid*32 + i*8;
        gload16(Bt + (n0 + (size_t)(r + srow8))*K + k0 + scol, &Bs[cur^1][r*64]);
      }
    }
    #pragma unroll
    for (int kk = 0; kk < 2; ++kk) {
      bf16x8 af[2], bfr[2];
      #pragma unroll
      for (int i=0;i<2;++i){
        const int arow = i*16 + l15;
        af[i]  = *(const bf16x8*)&As[cur][arow*64 + (((kk*4+lh) ^ (arow&7))<<3)];
      }
      #pragma unroll
      for (int n=0;n<2;++n){
        const int brow = wid*32 + n*16 + l15;
        bfr[n] = *(const bf16x8*)&Bs[cur][brow*64 + (((kk*4+lh) ^ (brow&7))<<3)];
      }
      #pragma unroll
      for (int mi=0;mi<2;++mi)
        #pragma unroll
        for (int ni=0;ni<2;++ni)
          MFMA16(af[mi], bfr[ni], acc[mi][ni]);
    }
    __syncthreads();
  }

  #pragma unroll
  for (int mi=0;mi<2;++mi){
    #pragma unroll
    for (int r=0;r<4;++r){
      size_t row = m0 + mi*16 + 4*lh + r;
      #pragma unroll
      for (int ni=0;ni<2;++ni){
        size_t col = n0 + wid*32 + ni*16 + l15;
        float v = acc[mi][ni][r];
        if (MODE==0) ((bf16*)outp)[row*(size_t)N + col] = (bf16)v;
        else if (MODE==1) ((float*)outp)[row*(size_t)N + col] = v + bias[col] + resid[row*(size_t)N + col];
        else { v += bias[col];
               ((bf16*)outp)[row*(size_t)N + col] =
                   (bf16)(0.5f*v*(1.0f + erff(v*0.70710678f))); }
      }
    }
  }
}

// ---- V rearrange for SA: vt[bh][d][s] = qkv[b*2048+s][2048 + h*64 + d] ----
__global__ __launch_bounds__(256) void vtsa_kernel(const bf16* __restrict__ qkv, bf16* __restrict__ vt)
{
  __shared__ bf16 t[32][33];
  const int b = blockIdx.z >> 4, h = blockIdx.z & 15;
  const int s0 = blockIdx.x*32, d0 = blockIdx.y*32;
  const int tx = threadIdx.x & 31, ty = threadIdx.x >> 5;
  #pragma unroll
  for (int i = ty; i < 32; i += 8)
    t[i][tx] = qkv[(size_t)(b*2048 + s0+i)*3072 + 2048 + h*64 + d0 + tx];
  __syncthreads();
  #pragma unroll
  for (int i = ty; i < 32; i += 8)
    vt[((size_t)blockIdx.z*64 + d0+i)*2048 + s0 + tx] = t[tx][i];
}

// ---- CA KV rearrange (pad 77 -> 128, zero fill) ----
__global__ __launch_bounds__(256) void kvca_re(const bf16* __restrict__ kvca,
    bf16* __restrict__ kpad, bf16* __restrict__ vtca)
{
  int idx = blockIdx.x*256 + threadIdx.x;           // over 2*16*128*64 = 262144
  if (idx >= 2*16*128*64) return;
  int d = idx & 63, s = (idx>>6) & 127, h = (idx>>13) & 15, b = idx>>17;
  bf16 kv = (bf16)0.f, vv = (bf16)0.f;
  if (s < 77) {
    kv = kvca[(size_t)(b*77+s)*2048 + h*64 + d];
    vv = kvca[(size_t)(b*77+s)*2048 + 1024 + h*64 + d];
  }
  kpad[idx] = kv;                                   // [b][h][s][d]
  vtca[(((size_t)(b*16+h)*64 + d)<<7) + s] = vv;    // [b][h][d][s], stride 128
}

// ---- Flash attention v6: unpaired 1-tile-per-block, 3 blocks/CU ----
template<int CAUSAL>
__global__ __launch_bounds__(256) void flash6(
    const bf16* __restrict__ qb, long q_bstride, long qstride,
    const bf16* __restrict__ kb0, long k_bstride, long k_hstride, long kstride,
    const bf16* __restrict__ vtb, long vt_bhstride, long vtstride,
    bf16* __restrict__ out, int skv)
{
  __shared__ __align__(16) bf16 Ks[2][64*64];
  __shared__ __align__(16) bf16 Vs[2][64*64];
  __shared__ __align__(16) bf16 Ps[4][16*68];
  const int tid = threadIdx.x;
  const int w = tid >> 6, lane = tid & 63, l15 = lane & 15, lh = lane >> 4;
  const int bid = blockIdx.x;
  const int bh   = (bid & 7) + 8*((bid >> 3) & 3);   // bh&7 == bid&7 -> XCD-resident K/V
  const int tile = 31 - (bid >> 5);                  // longest-first dispatch
  const int b = bh >> 4, h = bh & 15;
  const int q0 = tile * 64;
  const int nkb   = CAUSAL ? tile + 1 : ((skv + 63) >> 6);
  const int nfull = CAUSAL ? tile     : (skv >> 6);

  const bf16* kbase = kb0 + (size_t)b*k_bstride + (size_t)h*k_hstride;
  const bf16* vbase = vtb + (size_t)bh*vt_bhstride;
  const int sr0 = tid >> 3, sslot = tid & 7;

  const bf16* qrow = qb + (size_t)b*q_bstride + (size_t)h*64
                        + (size_t)(q0 + w*16 + l15)*qstride;
  bf16x8 qf0 = *(const bf16x8*)(qrow + 8*lh);
  bf16x8 qf1 = *(const bf16x8*)(qrow + 32 + 8*lh);

  f32x4 o[4];
  #pragma unroll
  for (int i=0;i<4;++i) o[i] = (f32x4){0.f,0.f,0.f,0.f};
  float lacc[4] = {0.f,0.f,0.f,0.f};

  bf16x8 kreg[2], vreg[2];
  #pragma unroll
  for (int i=0;i<2;++i){
    int r = sr0 + 32*i;
    kreg[i] = *(const bf16x8*)(kbase + (size_t)r*kstride + sslot*8);
    vreg[i] = *(const bf16x8*)(vbase + (size_t)r*vtstride + sslot*8);
  }

  for (int kb = 0; kb < nkb; ++kb) {
    const int buf = kb & 1;
    #pragma unroll
    for (int i=0;i<2;++i){
      int r = sr0 + 32*i;
      int ps = (sslot ^ (r & 7)) * 8;
      *(bf16x8*)&Ks[buf][r*64 + ps] = kreg[i];
      *(bf16x8*)&Vs[buf][r*64 + ps] = vreg[i];
    }
    __syncthreads();
    if (kb + 1 < nkb) {
      #pragma unroll
      for (int i=0;i<2;++i){
        int r = sr0 + 32*i;
        kreg[i] = *(const bf16x8*)(kbase + (size_t)((kb+1)*64 + r)*kstride + sslot*8);
        vreg[i] = *(const bf16x8*)(vbase + (size_t)r*vtstride + (kb+1)*64 + sslot*8);
      }
    }
    f32x4 sf[4];
    __builtin_amdgcn_s_setprio(1);
    #pragma unroll
    for (int ni = 0; ni < 4; ++ni) {
      int kr = ni*16 + l15;
      bf16x8 kf0 = *(const bf16x8*)&Ks[buf][kr*64 + (((lh  ) ^ (kr&7))<<3)];
      bf16x8 kf1 = *(const bf16x8*)&Ks[buf][kr*64 + (((lh+4) ^ (kr&7))<<3)];
      f32x4 z = (f32x4){0.f,0.f,0.f,0.f};
      MFMA16(qf0, kf0, z);
      MFMA16(qf1, kf1, z);
      sf[ni] = z;
    }
    __builtin_amdgcn_s_setprio(0);
    if (kb >= nfull) {
      #pragma unroll
      for (int ni=0;ni<4;++ni){
        int col = kb*64 + ni*16 + l15;
        #pragma unroll
        for (int r=0;r<4;++r){
          int rowg = q0 + w*16 + 4*lh + r;
          if (col >= skv || (CAUSAL && col > rowg)) sf[ni][r] = -1e30f;
        }
      }
    }
    #pragma unroll
    for (int ni=0;ni<4;++ni){
      #pragma unroll
      for (int r=0;r<4;++r){
        float p = __expf(sf[ni][r]);
        lacc[r] += p;
        Ps[w][(4*lh + r)*68 + ni*16 + l15] = (bf16)p;
      }
    }
    bf16x8 pa0 = *(const bf16x8*)&Ps[w][l15*68 + 8*lh];
    bf16x8 pa1 = *(const bf16x8*)&Ps[w][l15*68 + 32 + 8*lh];
    __builtin_amdgcn_s_setprio(1);
    #pragma unroll
    for (int nd=0;nd<4;++nd){
      int vr = nd*16 + l15;
      bf16x8 vf0 = *(const bf16x8*)&Vs[buf][vr*64 + (((lh  ) ^ (vr&7))<<3)];
      bf16x8 vf1 = *(const bf16x8*)&Vs[buf][vr*64 + (((lh+4) ^ (vr&7))<<3)];
      MFMA16(pa0, vf0, o[nd]);
      MFMA16(pa1, vf1, o[nd]);
    }
    __builtin_amdgcn_s_setprio(0);
  }
  float lr[4];
  #pragma unroll
  for (int r=0;r<4;++r) lr[r] = lacc[r];
  #pragma unroll
  for (int off=1; off<16; off<<=1)
    #pragma unroll
    for (int r=0;r<4;++r) lr[r] += __shfl_xor(lr[r], off);
  #pragma unroll
  for (int nd=0;nd<4;++nd)
    #pragma unroll
    for (int r=0;r<4;++r){
      int rowg = q0 + w*16 + 4*lh + r;
      out[(size_t)(b*2048 + rowg)*1024 + h*64 + nd*16 + l15] =
          (bf16)(o[nd][r] / lr[r]);
    }
}

// ---- host ----
struct Bump { char* base; size_t off;
  void* get(size_t bytes){ void* p = base + off; off += (bytes + 255) & ~(size_t)255; return p; } };

extern "C" void kernel_launch(void* const* d_in, const int* in_sizes, int n_in,
                              void* d_out, int out_size, void* d_ws, size_t ws_size,
                              hipStream_t stream)
{
  const float* x        = (const float*)d_in[0];
  const float* cond     = (const float*)d_in[1];
  const float* Wqkv     = (const float*)d_in[2];
  const float* Wproj_sa = (const float*)d_in[3];
  const float* bproj_sa = (const float*)d_in[4];
  const float* g1       = (const float*)d_in[5];
  const float* b1       = (const float*)d_in[6];
  const float* Wq_ca    = (const float*)d_in[7];
  const float* Wkv_ca   = (const float*)d_in[8];
  const float* Wproj_ca = (const float*)d_in[9];
  const float* bproj_ca = (const float*)d_in[10];
  const float* g2       = (const float*)d_in[11];
  const float* b2       = (const float*)d_in[12];
  const float* Wff1     = (const float*)d_in[13];
  const float* bff1     = (const float*)d_in[14];
  const float* Wff2     = (const float*)d_in[15];
  const float* bff2     = (const float*)d_in[16];
  const float* g3       = (const float*)d_in[17];
  const float* b3       = (const float*)d_in[18];

  Bump bump{(char*)d_ws, 0};
  bf16* wqkvT    = (bf16*)bump.get((size_t)3072*1024*2);
  bf16* wprojSaT = (bf16*)bump.get((size_t)1024*1024*2);
  bf16* wqCaT    = (bf16*)bump.get((size_t)1024*1024*2);
  bf16* wkvCaT   = (bf16*)bump.get((size_t)2048*768*2);
  bf16* wprojCaT = (bf16*)bump.get((size_t)1024*1024*2);
  bf16* wff1T    = (bf16*)bump.get((size_t)4096*1024*2);
  bf16* wff2T    = (bf16*)bump.get((size_t)1024*4096*2);
  bf16* condb    = (bf16*)bump.get((size_t)154*768*2);
  bf16* xn       = (bf16*)bump.get((size_t)4096*1024*2);
  bf16* qkv      = (bf16*)bump.get((size_t)4096*3072*2);   // 25165824 B
  bf16* vt_sa    = (bf16*)bump.get((size_t)2*16*64*2048*2);//  8388608 B (follows qkv)
  bf16* attn     = (bf16*)bump.get((size_t)4096*1024*2);
  bf16* kvca     = (bf16*)bump.get((size_t)154*2048*2);
  bf16* kpad     = (bf16*)bump.get((size_t)2*16*128*64*2);
  bf16* vtca     = (bf16*)bump.get((size_t)2*16*64*128*2);
  bf16* h1   = qkv;             // FF hidden: qkv+vt_sa dead by FF1
  bf16* qca  = vt_sa;           // CA query: vt_sa dead after SA flash
  float* x1  = (float*)d_out;   // residual stream lives in d_out

  // weight prep + LN1 fused in one launch (independent work, runs concurrently)
  prep_ln<<<dim3(8180), 256, 0, stream>>>(
      Wqkv, wqkvT, Wproj_sa, wprojSaT, Wq_ca, wqCaT, Wkv_ca, wkvCaT,
      Wproj_ca, wprojCaT, Wff1, wff1T, Wff2, wff2T, cond, condb,
      x, g1, b1, xn);

  // self-attention
  gemm256p<0><<<dim3(12,16), 512, 0, stream>>>(xn, wqkvT, nullptr, nullptr, qkv, 4096, 3072, 1024);
  vtsa_kernel<<<dim3(64,2,32), 256, 0, stream>>>(qkv, vt_sa);
  flash6<1><<<dim3(1024), 256, 0, stream>>>(
      qkv,        (long)2048*3072, 3072,
      qkv + 1024, (long)2048*3072, 64, 3072,
      vt_sa,      (long)64*2048, 2048,
      attn, 2048);
  gemm32<1><<<dim3(8,128), 256, 0, stream>>>(attn, wprojSaT, bproj_sa, x, x1, 4096, 1024, 1024);

  // cross-attention
  ln_kernel<<<dim3(4096), 256, 0, stream>>>(x1, g2, b2, xn);
  gemm32<0><<<dim3(8,128), 256, 0, stream>>>(xn, wqCaT, nullptr, nullptr, qca, 4096, 1024, 1024);
  gemm_bt<0><<<dim3(16,2), 256, 0, stream>>>(condb, wkvCaT, nullptr, nullptr, kvca, 154, 2048, 768);
  kvca_re<<<dim3(1024), 256, 0, stream>>>(kvca, kpad, vtca);
  flash6<0><<<dim3(1024), 256, 0, stream>>>(
      qca,  (long)2048*1024, 1024,
      kpad, (long)16*128*64, (long)128*64, 64,
      vtca, (long)64*128, 128,
      attn, 77);
  gemm32<1><<<dim3(8,128), 256, 0, stream>>>(attn, wprojCaT, bproj_ca, x1, x1, 4096, 1024, 1024);

  // FFN
  ln_kernel<<<dim3(4096), 256, 0, stream>>>(x1, g3, b3, xn);
  gemm256p<2><<<dim3(16,16), 512, 0, stream>>>(xn, wff1T, bff1, nullptr, h1, 4096, 4096, 1024);
  gemm32<1><<<dim3(8,128), 256, 0, stream>>>(h1, wff2T, bff2, x1, d_out, 4096, 1024, 4096);

  (void)in_sizes; (void)n_in; (void)out_size; (void)ws_size;
}

// Round 21
// 299.203 us; speedup vs baseline: 1.0295x; 1.0117x over previous
//
#include <hip/hip_runtime.h>

using bf16   = __bf16;
using bf16x8 = __attribute__((ext_vector_type(8))) bf16;
using bf16x4 = __attribute__((ext_vector_type(4))) bf16;
using f32x4  = __attribute__((ext_vector_type(4))) float;

#define DEV static __device__ __forceinline__

DEV void MFMA16(bf16x8 a, bf16x8 b, f32x4& c){
  c = __builtin_amdgcn_mfma_f32_16x16x32_bf16(a, b, c, 0, 0, 0);
}

// async global->LDS DMA, 16B per lane; lds dest is wave-uniform base + lane*16
DEV void gload16(const bf16* g, bf16* lds){
  __builtin_amdgcn_global_load_lds(
      (const __attribute__((address_space(1))) void*)g,
      (__attribute__((address_space(3))) void*)lds, 16, 0, 0);
}

// ---- vectorized transpose-cast tile: 32 rows x 128 cols of in[R?][C],
// out[c][r] = bf16(in[r][c] * (c<nscale ? scale:1)). float4 loads, bf16x8 stores.
DEV void tcast4_dev(const float* __restrict__ in, bf16* __restrict__ out,
                    int R, int C, int bx, int by, float scale, int nscale,
                    int tid, float (*t)[129])
{
  const int c0 = bx*128, r0 = by*32;
  #pragma unroll
  for (int i = 0; i < 4; ++i){
    int row = i*8 + (tid >> 5);
    int col = (tid & 31) * 4;
    const float4 v = *(const float4*)&in[(size_t)(r0+row)*C + c0 + col];
    t[row][col+0]=v.x; t[row][col+1]=v.y; t[row][col+2]=v.z; t[row][col+3]=v.w;
  }
  __syncthreads();
  const int c = tid >> 1, rh = (tid & 1) * 16;
  const float sc = (c0 + c < nscale) ? scale : 1.f;
  bf16 tmp[16];
  #pragma unroll
  for (int j = 0; j < 16; ++j) tmp[j] = (bf16)(t[rh+j][c] * sc);
  bf16* o = out + (size_t)(c0+c)*R + r0 + rh;
  *(bf16x8*)o       = *(bf16x8*)&tmp[0];
  *(bf16x8*)(o + 8) = *(bf16x8*)&tmp[8];
}

// ---- device LayerNorm row (256 threads, row of 1024 fp32 -> bf16) ----
DEV void ln_dev(const float* __restrict__ x, const float* __restrict__ gw,
                const float* __restrict__ bw, bf16* __restrict__ y,
                int row, int tid, float (*red)[4])
{
  const float4 v = ((const float4*)(x + (size_t)row*1024))[tid];
  float s  = v.x+v.y+v.z+v.w;
  float s2 = v.x*v.x+v.y*v.y+v.z*v.z+v.w*v.w;
  #pragma unroll
  for (int off=32; off>=1; off>>=1){ s += __shfl_down(s,off); s2 += __shfl_down(s2,off); }
  const int wid = tid>>6, lane = tid&63;
  if (lane==0){ red[0][wid]=s; red[1][wid]=s2; }
  __syncthreads();
  s  = red[0][0]+red[0][1]+red[0][2]+red[0][3];
  s2 = red[1][0]+red[1][1]+red[1][2]+red[1][3];
  const float m  = s*(1.f/1024.f);
  const float rs = rsqrtf(s2*(1.f/1024.f) - m*m + 1e-5f);
  const float4 gv = ((const float4*)gw)[tid];
  const float4 bv = ((const float4*)bw)[tid];
  bf16* yr = y + (size_t)row*1024 + tid*4;
  yr[0] = (bf16)((v.x-m)*rs*gv.x + bv.x);
  yr[1] = (bf16)((v.y-m)*rs*gv.y + bv.y);
  yr[2] = (bf16)((v.z-m)*rs*gv.z + bv.z);
  yr[3] = (bf16)((v.w-m)*rs*gv.w + bv.w);
}

// ---- merged prep + LN1 (independent work, one launch -> concurrent) ----
__global__ __launch_bounds__(256) void prep_ln(
    const float* Wqkv, bf16* wqkvT, const float* Wps, bf16* wpsT,
    const float* Wqc, bf16* wqcT, const float* Wkvc, bf16* wkvcT,
    const float* Wpc, bf16* wpcT, const float* Wf1, bf16* wf1T,
    const float* Wf2, bf16* wf2T, const float* cond, bf16* condb,
    const float* x, const float* g1, const float* b1, bf16* xn)
{
  __shared__ float t[32][129];
  __shared__ float red[2][4];
  const int bid = blockIdx.x, tid = threadIdx.x;
  if      (bid <  768) tcast4_dev(Wqkv, wqkvT, 1024, 3072, bid%24,        bid/24,        0.125f, 1024, tid, t);
  else if (bid < 1024) tcast4_dev(Wps,  wpsT,  1024, 1024, (bid-768)%8,   (bid-768)/8,   1.f, 0, tid, t);
  else if (bid < 1280) tcast4_dev(Wqc,  wqcT,  1024, 1024, (bid-1024)%8,  (bid-1024)/8,  0.125f, 1024, tid, t);
  else if (bid < 1664) tcast4_dev(Wkvc, wkvcT,  768, 2048, (bid-1280)%16, (bid-1280)/16, 1.f, 0, tid, t);
  else if (bid < 1920) tcast4_dev(Wpc,  wpcT,  1024, 1024, (bid-1664)%8,  (bid-1664)/8,  1.f, 0, tid, t);
  else if (bid < 2944) tcast4_dev(Wf1,  wf1T,  1024, 4096, (bid-1920)%32, (bid-1920)/32, 1.f, 0, tid, t);
  else if (bid < 3968) tcast4_dev(Wf2,  wf2T,  4096, 1024, (bid-2944)%8,  (bid-2944)/8,  1.f, 0, tid, t);
  else if (bid < 4084) {
    int i = (bid-3968)*256 + tid;      // float4 index over 118272/4 = 29568
    if (i < 29568) {
      const float4 v = ((const float4*)cond)[i];
      bf16 o[4] = {(bf16)v.x,(bf16)v.y,(bf16)v.z,(bf16)v.w};
      *(bf16x4*)&condb[i*4] = *(bf16x4*)o;
    }
  } else {
    ln_dev(x, g1, b1, xn, bid - 4084, tid, red);
  }
}

// ---- LayerNorm standalone (for LN2/LN3) ----
__global__ __launch_bounds__(256) void ln_kernel(const float* __restrict__ x,
    const float* __restrict__ gw, const float* __restrict__ bw, bf16* __restrict__ y)
{
  __shared__ float red[2][4];
  ln_dev(x, gw, bw, y, blockIdx.x, threadIdx.x, red);
}

// ---- GEMM 256x256 PHASED (T3+T4): 8 waves, BK=64, counted-vmcnt pipeline ----
template<int MODE>
__global__ __launch_bounds__(512) void gemm256p(
    const bf16* __restrict__ A, const bf16* __restrict__ Bt,
    const float* __restrict__ bias, const float* resid,
    void* outp, int M, int N, int K)
{
  __shared__ __align__(16) bf16 As[2][256*64];
  __shared__ __align__(16) bf16 Bs[2][256*64];
  const int tid = threadIdx.x;
  const int lane = tid & 63, wid = tid >> 6;       // wid 0..7
  const int l15 = lane & 15, lh = lane >> 4;
  const int wm = wid >> 2, wn = wid & 3;           // 2 x 4 wave grid

  const int nwg = gridDim.x * gridDim.y;
  const int lin = blockIdx.y * gridDim.x + blockIdx.x;
  const int wg  = (lin & 7) * (nwg >> 3) + (lin >> 3);
  const size_t m0 = (size_t)(wg / gridDim.x) * 256;
  const size_t n0 = (size_t)(wg % gridDim.x) * 256;

  f32x4 acc[8][4];
  #pragma unroll
  for (int i=0;i<8;++i)
    #pragma unroll
    for (int j=0;j<4;++j) acc[i][j] = (f32x4){0.f,0.f,0.f,0.f};

  const int srow8 = lane >> 3;
  const int scol  = ((lane & 7) ^ srow8) * 8;
  const int NT = K >> 6;

  auto stageH = [&](int t, int j){
    if (t >= NT) return;
    const int k0 = t << 6;
    const int buf = t & 1;
    const int hl = j & 1;
    const bf16* src = (j < 2) ? A : Bt;
    const size_t base = (j < 2) ? m0 : n0;
    bf16* dst = (j < 2) ? &As[buf][0] : &Bs[buf][0];
    #pragma unroll
    for (int i = 0; i < 2; ++i) {
      int r = hl*128 + wid*16 + i*8;
      gload16(src + (base + (size_t)(r + srow8))*K + k0 + scol, dst + r*64);
    }
  };
  auto rdA = [&](int buf, int mh, int kk, bf16x8* dst){
    #pragma unroll
    for (int i=0;i<4;++i){
      int row = wm*128 + (mh*4+i)*16 + l15;
      dst[i] = *(const bf16x8*)&As[buf][row*64 + (((kk*4+lh) ^ (row&7))<<3)];
    }
  };
  auto rdB = [&](int buf, int kk, bf16x8* dst){
    #pragma unroll
    for (int n=0;n<4;++n){
      int row = wn*64 + n*16 + l15;
      dst[n] = *(const bf16x8*)&Bs[buf][row*64 + (((kk*4+lh) ^ (row&7))<<3)];
    }
  };

  stageH(0,0); stageH(0,1); stageH(0,2); stageH(0,3);
  stageH(1,0); stageH(1,1);
  if (NT > 1) asm volatile("s_waitcnt vmcnt(4)" ::: "memory");
  else        asm volatile("s_waitcnt vmcnt(0)" ::: "memory");
  __builtin_amdgcn_sched_barrier(0);
  __builtin_amdgcn_s_barrier();

  for (int t = 0; t < NT; ++t) {
    const int buf = t & 1;
    bf16x8 af0k0[4], af0k1[4], af1k0[4], af1k1[4], bfr0[4], bfr1[4];
    rdA(buf,0,0,af0k0); rdA(buf,0,1,af0k1); rdB(buf,0,bfr0);
    stageH(t+1,2);
    __builtin_amdgcn_s_barrier();
    asm volatile("s_waitcnt lgkmcnt(0)" ::: "memory");
    __builtin_amdgcn_sched_barrier(0);
    __builtin_amdgcn_s_setprio(1);
    #pragma unroll
    for (int mi=0;mi<4;++mi)
      #pragma unroll
      for (int ni=0;ni<4;++ni) MFMA16(af0k0[mi], bfr0[ni], acc[mi][ni]);
    __builtin_amdgcn_s_setprio(0);
    __builtin_amdgcn_sched_barrier(0);
    __builtin_amdgcn_s_barrier();
    rdA(buf,1,0,af1k0); rdA(buf,1,1,af1k1); rdB(buf,1,bfr1);
    stageH(t+1,3);
    __builtin_amdgcn_s_barrier();
    asm volatile("s_waitcnt lgkmcnt(0)" ::: "memory");
    __builtin_amdgcn_sched_barrier(0);
    __builtin_amdgcn_s_setprio(1);
    #pragma unroll
    for (int mi=0;mi<4;++mi)
      #pragma unroll
      for (int ni=0;ni<4;++ni) MFMA16(af1k0[mi], bfr0[ni], acc[4+mi][ni]);
    __builtin_amdgcn_s_setprio(0);
    __builtin_amdgcn_sched_barrier(0);
    __builtin_amdgcn_s_barrier();
    stageH(t+2,0);
    stageH(t+2,1);
    __builtin_amdgcn_s_setprio(1);
    #pragma unroll
    for (int mi=0;mi<4;++mi)
      #pragma unroll
      for (int ni=0;ni<4;++ni) MFMA16(af0k1[mi], bfr1[ni], acc[mi][ni]);
    #pragma unroll
    for (int mi=0;mi<4;++mi)
      #pragma unroll
      for (int ni=0;ni<4;++ni) MFMA16(af1k1[mi], bfr1[ni], acc[4+mi][ni]);
    __builtin_amdgcn_s_setprio(0);
    if (t + 2 < NT) asm volatile("s_waitcnt vmcnt(4)" ::: "memory");
    else            asm volatile("s_waitcnt vmcnt(0)" ::: "memory");
    __builtin_amdgcn_sched_barrier(0);
    __builtin_amdgcn_s_barrier();
  }

  #pragma unroll
  for (int mi=0;mi<8;++mi){
    #pragma unroll
    for (int r=0;r<4;++r){
      size_t row = m0 + wm*128 + mi*16 + 4*lh + r;
      #pragma unroll
      for (int ni=0;ni<4;++ni){
        size_t col = n0 + wn*64 + ni*16 + l15;
        float v = acc[mi][ni][r];
        if (MODE==0) ((bf16*)outp)[row*(size_t)N + col] = (bf16)v;
        else if (MODE==1) ((float*)outp)[row*(size_t)N + col] = v + bias[col] + resid[row*(size_t)N + col];
        else { v += bias[col];
               ((bf16*)outp)[row*(size_t)N + col] =
                   (bf16)(0.5f*v*(1.0f + erff(v*0.70710678f))); }
      }
    }
  }
}

// ---- GEMM 32x128 body (BK=64, 2-phase dbuf, swizzled): As = 2*2048 bf16,
// Bs = 2*8192 bf16 carved from the caller's LDS. M-clamped staging + guarded
// C writes so any M works. mode: 0 = bf16 out, 1 = f32 out + bias + resid.
DEV void g32_body(bf16* As, bf16* Bs, size_t m0, size_t n0,
                  const bf16* __restrict__ A, const bf16* __restrict__ Bt,
                  const float* __restrict__ bias, const float* resid,
                  void* outp, int M, int N, int K, int mode, int tid)
{
  const int lane = tid & 63, wid = tid >> 6;
  const int l15 = lane & 15, lh = lane >> 4;

  f32x4 acc[2][2];
  #pragma unroll
  for (int i=0;i<2;++i)
    #pragma unroll
    for (int j=0;j<2;++j) acc[i][j] = (f32x4){0.f,0.f,0.f,0.f};

  const int srow8 = lane >> 3;
  const int scol  = ((lane & 7) ^ srow8) * 8;
  const int NT = K >> 6;

  auto stage = [&](int t, int buf){
    const int k0 = t << 6;
    {
      int r = wid*8;
      int ar = (int)m0 + r + srow8; if (ar >= M) ar = M - 1;
      gload16(A + (size_t)ar*K + k0 + scol, As + buf*2048 + r*64);
    }
    #pragma unroll
    for (int i = 0; i < 4; ++i) {
      int r = wid*32 + i*8;
      gload16(Bt + (n0 + (size_t)(r + srow8))*K + k0 + scol, Bs + buf*8192 + r*64);
    }
  };

  stage(0, 0);
  __syncthreads();

  for (int t = 0; t < NT; ++t) {
    const int cur = t & 1;
    if (t + 1 < NT) stage(t + 1, cur ^ 1);
    #pragma unroll
    for (int kk = 0; kk < 2; ++kk) {
      bf16x8 af[2], bfr[2];
      #pragma unroll
      for (int i=0;i<2;++i){
        const int arow = i*16 + l15;
        af[i]  = *(const bf16x8*)&As[cur*2048 + arow*64 + (((kk*4+lh) ^ (arow&7))<<3)];
      }
      #pragma unroll
      for (int n=0;n<2;++n){
        const int brow = wid*32 + n*16 + l15;
        bfr[n] = *(const bf16x8*)&Bs[cur*8192 + brow*64 + (((kk*4+lh) ^ (brow&7))<<3)];
      }
      #pragma unroll
      for (int mi=0;mi<2;++mi)
        #pragma unroll
        for (int ni=0;ni<2;++ni)
          MFMA16(af[mi], bfr[ni], acc[mi][ni]);
    }
    __syncthreads();
  }

  #pragma unroll
  for (int mi=0;mi<2;++mi){
    #pragma unroll
    for (int r=0;r<4;++r){
      size_t row = m0 + mi*16 + 4*lh + r;
      if (row < (size_t)M) {
        #pragma unroll
        for (int ni=0;ni<2;++ni){
          size_t col = n0 + wid*32 + ni*16 + l15;
          float v = acc[mi][ni][r];
          if (mode == 0) ((bf16*)outp)[row*(size_t)N + col] = (bf16)v;
          else ((float*)outp)[row*(size_t)N + col] = v + bias[col] + resid[row*(size_t)N + col];
        }
      }
    }
  }
}

// ---- GEMM 32x128 standalone (m-major XCD decode), 4 blocks/CU ----
template<int MODE>
__global__ __launch_bounds__(256) void gemm32(
    const bf16* __restrict__ A, const bf16* __restrict__ Bt,
    const float* __restrict__ bias, const float* resid,
    void* outp, int M, int N, int K)
{
  __shared__ __align__(16) bf16 As[2*32*64];
  __shared__ __align__(16) bf16 Bs[2*128*64];
  const int nwg = gridDim.x * gridDim.y;
  const int lin = blockIdx.y * gridDim.x + blockIdx.x;
  const int wg  = (lin & 7) * (nwg >> 3) + (lin >> 3);
  const size_t m0 = (size_t)(wg / gridDim.x) * 32;
  const size_t n0 = (size_t)(wg % gridDim.x) * 128;
  g32_body(As, Bs, m0, n0, A, Bt, bias, resid, outp, M, N, K, MODE, threadIdx.x);
}

// ---- fused qca GEMM (1024 blocks) + CA-KV GEMM (80 blocks) ----
// blocks [0,1024): qca = xn @ wqCaT^T (M=4096,N=1024,K=1024), XCD-swizzled.
// blocks [1024,1104): kvca = condb @ wkvCaT^T (M=154,N=2048,K=768).
__global__ __launch_bounds__(256) void qca_kv(
    const bf16* __restrict__ xn, const bf16* __restrict__ wqCaT, bf16* qca,
    const bf16* __restrict__ condb, const bf16* __restrict__ wkvCaT, bf16* kvca)
{
  __shared__ __align__(16) bf16 As[2*32*64];
  __shared__ __align__(16) bf16 Bs[2*128*64];
  const int bid = blockIdx.x;
  if (bid < 1024) {
    const int wg  = (bid & 7) * 128 + (bid >> 3);   // same m-major swizzle, nwg=1024
    const size_t m0 = (size_t)(wg >> 3) * 32;
    const size_t n0 = (size_t)(wg & 7) * 128;
    g32_body(As, Bs, m0, n0, xn, wqCaT, nullptr, nullptr, qca,
             4096, 1024, 1024, 0, threadIdx.x);
  } else {
    const int g = bid - 1024;                        // 80 blocks: 5 m x 16 n
    const size_t m0 = (size_t)(g / 16) * 32;
    const size_t n0 = (size_t)(g % 16) * 128;
    g32_body(As, Bs, m0, n0, condb, wkvCaT, nullptr, nullptr, kvca,
             154, 2048, 768, 0, threadIdx.x);
  }
}

// ---- V rearrange for SA: vt[bh][d][s] = qkv[b*2048+s][2048 + h*64 + d] ----
__global__ __launch_bounds__(256) void vtsa_kernel(const bf16* __restrict__ qkv, bf16* __restrict__ vt)
{
  __shared__ bf16 t[32][33];
  const int b = blockIdx.z >> 4, h = blockIdx.z & 15;
  const int s0 = blockIdx.x*32, d0 = blockIdx.y*32;
  const int tx = threadIdx.x & 31, ty = threadIdx.x >> 5;
  #pragma unroll
  for (int i = ty; i < 32; i += 8)
    t[i][tx] = qkv[(size_t)(b*2048 + s0+i)*3072 + 2048 + h*64 + d0 + tx];
  __syncthreads();
  #pragma unroll
  for (int i = ty; i < 32; i += 8)
    vt[((size_t)blockIdx.z*64 + d0+i)*2048 + s0 + tx] = t[tx][i];
}

// ---- CA KV rearrange (pad 77 -> 128, zero fill) ----
__global__ __launch_bounds__(256) void kvca_re(const bf16* __restrict__ kvca,
    bf16* __restrict__ kpad, bf16* __restrict__ vtca)
{
  int idx = blockIdx.x*256 + threadIdx.x;           // over 2*16*128*64 = 262144
  if (idx >= 2*16*128*64) return;
  int d = idx & 63, s = (idx>>6) & 127, h = (idx>>13) & 15, b = idx>>17;
  bf16 kv = (bf16)0.f, vv = (bf16)0.f;
  if (s < 77) {
    kv = kvca[(size_t)(b*77+s)*2048 + h*64 + d];
    vv = kvca[(size_t)(b*77+s)*2048 + 1024 + h*64 + d];
  }
  kpad[idx] = kv;                                   // [b][h][s][d]
  vtca[(((size_t)(b*16+h)*64 + d)<<7) + s] = vv;    // [b][h][d][s], stride 128
}

// ---- Flash attention v6: unpaired 1-tile-per-block, 3 blocks/CU ----
template<int CAUSAL>
__global__ __launch_bounds__(256) void flash6(
    const bf16* __restrict__ qb, long q_bstride, long qstride,
    const bf16* __restrict__ kb0, long k_bstride, long k_hstride, long kstride,
    const bf16* __restrict__ vtb, long vt_bhstride, long vtstride,
    bf16* __restrict__ out, int skv)
{
  __shared__ __align__(16) bf16 Ks[2][64*64];
  __shared__ __align__(16) bf16 Vs[2][64*64];
  __shared__ __align__(16) bf16 Ps[4][16*68];
  const int tid = threadIdx.x;
  const int w = tid >> 6, lane = tid & 63, l15 = lane & 15, lh = lane >> 4;
  const int bid = blockIdx.x;
  const int bh   = (bid & 7) + 8*((bid >> 3) & 3);   // bh&7 == bid&7 -> XCD-resident K/V
  const int tile = 31 - (bid >> 5);                  // longest-first dispatch
  const int b = bh >> 4, h = bh & 15;
  const int q0 = tile * 64;
  const int nkb   = CAUSAL ? tile + 1 : ((skv + 63) >> 6);
  const int nfull = CAUSAL ? tile     : (skv >> 6);

  const bf16* kbase = kb0 + (size_t)b*k_bstride + (size_t)h*k_hstride;
  const bf16* vbase = vtb + (size_t)bh*vt_bhstride;
  const int sr0 = tid >> 3, sslot = tid & 7;

  const bf16* qrow = qb + (size_t)b*q_bstride + (size_t)h*64
                        + (size_t)(q0 + w*16 + l15)*qstride;
  bf16x8 qf0 = *(const bf16x8*)(qrow + 8*lh);
  bf16x8 qf1 = *(const bf16x8*)(qrow + 32 + 8*lh);

  f32x4 o[4];
  #pragma unroll
  for (int i=0;i<4;++i) o[i] = (f32x4){0.f,0.f,0.f,0.f};
  float lacc[4] = {0.f,0.f,0.f,0.f};

  bf16x8 kreg[2], vreg[2];
  #pragma unroll
  for (int i=0;i<2;++i){
    int r = sr0 + 32*i;
    kreg[i] = *(const bf16x8*)(kbase + (size_t)r*kstride + sslot*8);
    vreg[i] = *(const bf16x8*)(vbase + (size_t)r*vtstride + sslot*8);
  }

  for (int kb = 0; kb < nkb; ++kb) {
    const int buf = kb & 1;
    #pragma unroll
    for (int i=0;i<2;++i){
      int r = sr0 + 32*i;
      int ps = (sslot ^ (r & 7)) * 8;
      *(bf16x8*)&Ks[buf][r*64 + ps] = kreg[i];
      *(bf16x8*)&Vs[buf][r*64 + ps] = vreg[i];
    }
    __syncthreads();
    if (kb + 1 < nkb) {
      #pragma unroll
      for (int i=0;i<2;++i){
        int r = sr0 + 32*i;
        kreg[i] = *(const bf16x8*)(kbase + (size_t)((kb+1)*64 + r)*kstride + sslot*8);
        vreg[i] = *(const bf16x8*)(vbase + (size_t)r*vtstride + (kb+1)*64 + sslot*8);
      }
    }
    f32x4 sf[4];
    __builtin_amdgcn_s_setprio(1);
    #pragma unroll
    for (int ni = 0; ni < 4; ++ni) {
      int kr = ni*16 + l15;
      bf16x8 kf0 = *(const bf16x8*)&Ks[buf][kr*64 + (((lh  ) ^ (kr&7))<<3)];
      bf16x8 kf1 = *(const bf16x8*)&Ks[buf][kr*64 + (((lh+4) ^ (kr&7))<<3)];
      f32x4 z = (f32x4){0.f,0.f,0.f,0.f};
      MFMA16(qf0, kf0, z);
      MFMA16(qf1, kf1, z);
      sf[ni] = z;
    }
    __builtin_amdgcn_s_setprio(0);
    if (kb >= nfull) {
      #pragma unroll
      for (int ni=0;ni<4;++ni){
        int col = kb*64 + ni*16 + l15;
        #pragma unroll
        for (int r=0;r<4;++r){
          int rowg = q0 + w*16 + 4*lh + r;
          if (col >= skv || (CAUSAL && col > rowg)) sf[ni][r] = -1e30f;
        }
      }
    }
    #pragma unroll
    for (int ni=0;ni<4;++ni){
      #pragma unroll
      for (int r=0;r<4;++r){
        float p = __expf(sf[ni][r]);
        lacc[r] += p;
        Ps[w][(4*lh + r)*68 + ni*16 + l15] = (bf16)p;
      }
    }
    bf16x8 pa0 = *(const bf16x8*)&Ps[w][l15*68 + 8*lh];
    bf16x8 pa1 = *(const bf16x8*)&Ps[w][l15*68 + 32 + 8*lh];
    __builtin_amdgcn_s_setprio(1);
    #pragma unroll
    for (int nd=0;nd<4;++nd){
      int vr = nd*16 + l15;
      bf16x8 vf0 = *(const bf16x8*)&Vs[buf][vr*64 + (((lh  ) ^ (vr&7))<<3)];
      bf16x8 vf1 = *(const bf16x8*)&Vs[buf][vr*64 + (((lh+4) ^ (vr&7))<<3)];
      MFMA16(pa0, vf0, o[nd]);
      MFMA16(pa1, vf1, o[nd]);
    }
    __builtin_amdgcn_s_setprio(0);
  }
  float lr[4];
  #pragma unroll
  for (int r=0;r<4;++r) lr[r] = lacc[r];
  #pragma unroll
  for (int off=1; off<16; off<<=1)
    #pragma unroll
    for (int r=0;r<4;++r) lr[r] += __shfl_xor(lr[r], off);
  #pragma unroll
  for (int nd=0;nd<4;++nd)
    #pragma unroll
    for (int r=0;r<4;++r){
      int rowg = q0 + w*16 + 4*lh + r;
      out[(size_t)(b*2048 + rowg)*1024 + h*64 + nd*16 + l15] =
          (bf16)(o[nd][r] / lr[r]);
    }
}

// ---- host ----
struct Bump { char* base; size_t off;
  void* get(size_t bytes){ void* p = base + off; off += (bytes + 255) & ~(size_t)255; return p; } };

extern "C" void kernel_launch(void* const* d_in, const int* in_sizes, int n_in,
                              void* d_out, int out_size, void* d_ws, size_t ws_size,
                              hipStream_t stream)
{
  const float* x        = (const float*)d_in[0];
  const float* cond     = (const float*)d_in[1];
  const float* Wqkv     = (const float*)d_in[2];
  const float* Wproj_sa = (const float*)d_in[3];
  const float* bproj_sa = (const float*)d_in[4];
  const float* g1       = (const float*)d_in[5];
  const float* b1       = (const float*)d_in[6];
  const float* Wq_ca    = (const float*)d_in[7];
  const float* Wkv_ca   = (const float*)d_in[8];
  const float* Wproj_ca = (const float*)d_in[9];
  const float* bproj_ca = (const float*)d_in[10];
  const float* g2       = (const float*)d_in[11];
  const float* b2       = (const float*)d_in[12];
  const float* Wff1     = (const float*)d_in[13];
  const float* bff1     = (const float*)d_in[14];
  const float* Wff2     = (const float*)d_in[15];
  const float* bff2     = (const float*)d_in[16];
  const float* g3       = (const float*)d_in[17];
  const float* b3       = (const float*)d_in[18];

  Bump bump{(char*)d_ws, 0};
  bf16* wqkvT    = (bf16*)bump.get((size_t)3072*1024*2);
  bf16* wprojSaT = (bf16*)bump.get((size_t)1024*1024*2);
  bf16* wqCaT    = (bf16*)bump.get((size_t)1024*1024*2);
  bf16* wkvCaT   = (bf16*)bump.get((size_t)2048*768*2);
  bf16* wprojCaT = (bf16*)bump.get((size_t)1024*1024*2);
  bf16* wff1T    = (bf16*)bump.get((size_t)4096*1024*2);
  bf16* wff2T    = (bf16*)bump.get((size_t)1024*4096*2);
  bf16* condb    = (bf16*)bump.get((size_t)154*768*2);
  bf16* xn       = (bf16*)bump.get((size_t)4096*1024*2);
  bf16* qkv      = (bf16*)bump.get((size_t)4096*3072*2);   // 25165824 B
  bf16* vt_sa    = (bf16*)bump.get((size_t)2*16*64*2048*2);//  8388608 B (follows qkv)
  bf16* attn     = (bf16*)bump.get((size_t)4096*1024*2);
  bf16* kvca     = (bf16*)bump.get((size_t)154*2048*2);
  bf16* kpad     = (bf16*)bump.get((size_t)2*16*128*64*2);
  bf16* vtca     = (bf16*)bump.get((size_t)2*16*64*128*2);
  bf16* h1   = qkv;             // FF hidden: qkv+vt_sa dead by FF1
  bf16* qca  = vt_sa;           // CA query: vt_sa dead after SA flash
  float* x1  = (float*)d_out;   // residual stream lives in d_out

  // weight prep + LN1 fused in one launch (independent work, runs concurrently)
  prep_ln<<<dim3(8180), 256, 0, stream>>>(
      Wqkv, wqkvT, Wproj_sa, wprojSaT, Wq_ca, wqCaT, Wkv_ca, wkvCaT,
      Wproj_ca, wprojCaT, Wff1, wff1T, Wff2, wff2T, cond, condb,
      x, g1, b1, xn);

  // self-attention
  gemm256p<0><<<dim3(12,16), 512, 0, stream>>>(xn, wqkvT, nullptr, nullptr, qkv, 4096, 3072, 1024);
  vtsa_kernel<<<dim3(64,2,32), 256, 0, stream>>>(qkv, vt_sa);
  flash6<1><<<dim3(1024), 256, 0, stream>>>(
      qkv,        (long)2048*3072, 3072,
      qkv + 1024, (long)2048*3072, 64, 3072,
      vt_sa,      (long)64*2048, 2048,
      attn, 2048);
  gemm32<1><<<dim3(8,128), 256, 0, stream>>>(attn, wprojSaT, bproj_sa, x, x1, 4096, 1024, 1024);

  // cross-attention (qca GEMM + CA-KV GEMM fused into one launch)
  ln_kernel<<<dim3(4096), 256, 0, stream>>>(x1, g2, b2, xn);
  qca_kv<<<dim3(1104), 256, 0, stream>>>(xn, wqCaT, qca, condb, wkvCaT, kvca);
  kvca_re<<<dim3(1024), 256, 0, stream>>>(kvca, kpad, vtca);
  flash6<0><<<dim3(1024), 256, 0, stream>>>(
      qca,  (long)2048*1024, 1024,
      kpad, (long)16*128*64, (long)128*64, 64,
      vtca, (long)64*128, 128,
      attn, 77);
  gemm32<1><<<dim3(8,128), 256, 0, stream>>>(attn, wprojCaT, bproj_ca, x1, x1, 4096, 1024, 1024);

  // FFN
  ln_kernel<<<dim3(4096), 256, 0, stream>>>(x1, g3, b3, xn);
  gemm256p<2><<<dim3(16,16), 512, 0, stream>>>(xn, wff1T, bff1, nullptr, h1, 4096, 4096, 1024);
  gemm32<1><<<dim3(8,128), 256, 0, stream>>>(h1, wff2T, bff2, x1, d_out, 4096, 1024, 4096);

  (void)in_sizes; (void)n_in; (void)out_size; (void)ws_size;
}

// Round 22
// 295.808 us; speedup vs baseline: 1.0413x; 1.0115x over previous
//
#include <hip/hip_runtime.h>

using bf16   = __bf16;
using bf16x8 = __attribute__((ext_vector_type(8))) bf16;
using bf16x4 = __attribute__((ext_vector_type(4))) bf16;
using f32x4  = __attribute__((ext_vector_type(4))) float;

#define DEV static __device__ __forceinline__

DEV void MFMA16(bf16x8 a, bf16x8 b, f32x4& c){
  c = __builtin_amdgcn_mfma_f32_16x16x32_bf16(a, b, c, 0, 0, 0);
}

// async global->LDS DMA, 16B per lane; lds dest is wave-uniform base + lane*16
DEV void gload16(const bf16* g, bf16* lds){
  __builtin_amdgcn_global_load_lds(
      (const __attribute__((address_space(1))) void*)g,
      (__attribute__((address_space(3))) void*)lds, 16, 0, 0);
}

// ---- vectorized transpose-cast tile: 32 rows x 128 cols of in[R?][C],
// out[c][r] = bf16(in[r][c] * (c<nscale ? scale:1)). float4 loads, bf16x8 stores.
DEV void tcast4_dev(const float* __restrict__ in, bf16* __restrict__ out,
                    int R, int C, int bx, int by, float scale, int nscale,
                    int tid, float (*t)[129])
{
  const int c0 = bx*128, r0 = by*32;
  #pragma unroll
  for (int i = 0; i < 4; ++i){
    int row = i*8 + (tid >> 5);
    int col = (tid & 31) * 4;
    const float4 v = *(const float4*)&in[(size_t)(r0+row)*C + c0 + col];
    t[row][col+0]=v.x; t[row][col+1]=v.y; t[row][col+2]=v.z; t[row][col+3]=v.w;
  }
  __syncthreads();
  const int c = tid >> 1, rh = (tid & 1) * 16;
  const float sc = (c0 + c < nscale) ? scale : 1.f;
  bf16 tmp[16];
  #pragma unroll
  for (int j = 0; j < 16; ++j) tmp[j] = (bf16)(t[rh+j][c] * sc);
  bf16* o = out + (size_t)(c0+c)*R + r0 + rh;
  *(bf16x8*)o       = *(bf16x8*)&tmp[0];
  *(bf16x8*)(o + 8) = *(bf16x8*)&tmp[8];
}

// ---- device LayerNorm row (256 threads, row of 1024 fp32 -> bf16) ----
DEV void ln_dev(const float* __restrict__ x, const float* __restrict__ gw,
                const float* __restrict__ bw, bf16* __restrict__ y,
                int row, int tid, float (*red)[4])
{
  const float4 v = ((const float4*)(x + (size_t)row*1024))[tid];
  float s  = v.x+v.y+v.z+v.w;
  float s2 = v.x*v.x+v.y*v.y+v.z*v.z+v.w*v.w;
  #pragma unroll
  for (int off=32; off>=1; off>>=1){ s += __shfl_down(s,off); s2 += __shfl_down(s2,off); }
  const int wid = tid>>6, lane = tid&63;
  if (lane==0){ red[0][wid]=s; red[1][wid]=s2; }
  __syncthreads();
  s  = red[0][0]+red[0][1]+red[0][2]+red[0][3];
  s2 = red[1][0]+red[1][1]+red[1][2]+red[1][3];
  const float m  = s*(1.f/1024.f);
  const float rs = rsqrtf(s2*(1.f/1024.f) - m*m + 1e-5f);
  const float4 gv = ((const float4*)gw)[tid];
  const float4 bv = ((const float4*)bw)[tid];
  bf16* yr = y + (size_t)row*1024 + tid*4;
  yr[0] = (bf16)((v.x-m)*rs*gv.x + bv.x);
  yr[1] = (bf16)((v.y-m)*rs*gv.y + bv.y);
  yr[2] = (bf16)((v.z-m)*rs*gv.z + bv.z);
  yr[3] = (bf16)((v.w-m)*rs*gv.w + bv.w);
}

// ---- merged prep + LN1 (independent work, one launch -> concurrent) ----
__global__ __launch_bounds__(256) void prep_ln(
    const float* Wqkv, bf16* wqkvT, const float* Wps, bf16* wpsT,
    const float* Wqc, bf16* wqcT, const float* Wkvc, bf16* wkvcT,
    const float* Wpc, bf16* wpcT, const float* Wf1, bf16* wf1T,
    const float* Wf2, bf16* wf2T, const float* cond, bf16* condb,
    const float* x, const float* g1, const float* b1, bf16* xn)
{
  __shared__ float t[32][129];
  __shared__ float red[2][4];
  const int bid = blockIdx.x, tid = threadIdx.x;
  if      (bid <  768) tcast4_dev(Wqkv, wqkvT, 1024, 3072, bid%24,        bid/24,        0.125f, 1024, tid, t);
  else if (bid < 1024) tcast4_dev(Wps,  wpsT,  1024, 1024, (bid-768)%8,   (bid-768)/8,   1.f, 0, tid, t);
  else if (bid < 1280) tcast4_dev(Wqc,  wqcT,  1024, 1024, (bid-1024)%8,  (bid-1024)/8,  0.125f, 1024, tid, t);
  else if (bid < 1664) tcast4_dev(Wkvc, wkvcT,  768, 2048, (bid-1280)%16, (bid-1280)/16, 1.f, 0, tid, t);
  else if (bid < 1920) tcast4_dev(Wpc,  wpcT,  1024, 1024, (bid-1664)%8,  (bid-1664)/8,  1.f, 0, tid, t);
  else if (bid < 2944) tcast4_dev(Wf1,  wf1T,  1024, 4096, (bid-1920)%32, (bid-1920)/32, 1.f, 0, tid, t);
  else if (bid < 3968) tcast4_dev(Wf2,  wf2T,  4096, 1024, (bid-2944)%8,  (bid-2944)/8,  1.f, 0, tid, t);
  else if (bid < 4084) {
    int i = (bid-3968)*256 + tid;      // float4 index over 118272/4 = 29568
    if (i < 29568) {
      const float4 v = ((const float4*)cond)[i];
      bf16 o[4] = {(bf16)v.x,(bf16)v.y,(bf16)v.z,(bf16)v.w};
      *(bf16x4*)&condb[i*4] = *(bf16x4*)o;
    }
  } else {
    ln_dev(x, g1, b1, xn, bid - 4084, tid, red);
  }
}

// ---- LayerNorm standalone (for LN3) ----
__global__ __launch_bounds__(256) void ln_kernel(const float* __restrict__ x,
    const float* __restrict__ gw, const float* __restrict__ bw, bf16* __restrict__ y)
{
  __shared__ float red[2][4];
  ln_dev(x, gw, bw, y, blockIdx.x, threadIdx.x, red);
}

// ---- merged LN2 + CA-KV rearrange (independent work) ----
// blocks [0,4096): LN2 rows; [4096,5120): kvca_re over 262144 elems
__global__ __launch_bounds__(256) void ln_re(
    const float* __restrict__ x1, const float* __restrict__ g2,
    const float* __restrict__ b2, bf16* __restrict__ xn,
    const bf16* __restrict__ kvca, bf16* __restrict__ kpad, bf16* __restrict__ vtca)
{
  __shared__ float red[2][4];
  const int bid = blockIdx.x, tid = threadIdx.x;
  if (bid < 4096) {
    ln_dev(x1, g2, b2, xn, bid, tid, red);
  } else {
    int idx = (bid - 4096)*256 + tid;                 // over 2*16*128*64 = 262144
    int d = idx & 63, s = (idx>>6) & 127, h = (idx>>13) & 15, b = idx>>17;
    bf16 kv = (bf16)0.f, vv = (bf16)0.f;
    if (s < 77) {
      kv = kvca[(size_t)(b*77+s)*2048 + h*64 + d];
      vv = kvca[(size_t)(b*77+s)*2048 + 1024 + h*64 + d];
    }
    kpad[idx] = kv;                                   // [b][h][s][d]
    vtca[(((size_t)(b*16+h)*64 + d)<<7) + s] = vv;    // [b][h][d][s], stride 128
  }
}

// ---- GEMM 256x256 PHASED (T3+T4): 8 waves, BK=64, counted-vmcnt pipeline ----
template<int MODE>
__global__ __launch_bounds__(512) void gemm256p(
    const bf16* __restrict__ A, const bf16* __restrict__ Bt,
    const float* __restrict__ bias, const float* resid,
    void* outp, int M, int N, int K)
{
  __shared__ __align__(16) bf16 As[2][256*64];
  __shared__ __align__(16) bf16 Bs[2][256*64];
  const int tid = threadIdx.x;
  const int lane = tid & 63, wid = tid >> 6;       // wid 0..7
  const int l15 = lane & 15, lh = lane >> 4;
  const int wm = wid >> 2, wn = wid & 3;           // 2 x 4 wave grid

  const int nwg = gridDim.x * gridDim.y;
  const int lin = blockIdx.y * gridDim.x + blockIdx.x;
  const int wg  = (lin & 7) * (nwg >> 3) + (lin >> 3);
  const size_t m0 = (size_t)(wg / gridDim.x) * 256;
  const size_t n0 = (size_t)(wg % gridDim.x) * 256;

  f32x4 acc[8][4];
  #pragma unroll
  for (int i=0;i<8;++i)
    #pragma unroll
    for (int j=0;j<4;++j) acc[i][j] = (f32x4){0.f,0.f,0.f,0.f};

  const int srow8 = lane >> 3;
  const int scol  = ((lane & 7) ^ srow8) * 8;
  const int NT = K >> 6;

  auto stageH = [&](int t, int j){
    if (t >= NT) return;
    const int k0 = t << 6;
    const int buf = t & 1;
    const int hl = j & 1;
    const bf16* src = (j < 2) ? A : Bt;
    const size_t base = (j < 2) ? m0 : n0;
    bf16* dst = (j < 2) ? &As[buf][0] : &Bs[buf][0];
    #pragma unroll
    for (int i = 0; i < 2; ++i) {
      int r = hl*128 + wid*16 + i*8;
      gload16(src + (base + (size_t)(r + srow8))*K + k0 + scol, dst + r*64);
    }
  };
  auto rdA = [&](int buf, int mh, int kk, bf16x8* dst){
    #pragma unroll
    for (int i=0;i<4;++i){
      int row = wm*128 + (mh*4+i)*16 + l15;
      dst[i] = *(const bf16x8*)&As[buf][row*64 + (((kk*4+lh) ^ (row&7))<<3)];
    }
  };
  auto rdB = [&](int buf, int kk, bf16x8* dst){
    #pragma unroll
    for (int n=0;n<4;++n){
      int row = wn*64 + n*16 + l15;
      dst[n] = *(const bf16x8*)&Bs[buf][row*64 + (((kk*4+lh) ^ (row&7))<<3)];
    }
  };

  stageH(0,0); stageH(0,1); stageH(0,2); stageH(0,3);
  stageH(1,0); stageH(1,1);
  if (NT > 1) asm volatile("s_waitcnt vmcnt(4)" ::: "memory");
  else        asm volatile("s_waitcnt vmcnt(0)" ::: "memory");
  __builtin_amdgcn_sched_barrier(0);
  __builtin_amdgcn_s_barrier();

  for (int t = 0; t < NT; ++t) {
    const int buf = t & 1;
    bf16x8 af0k0[4], af0k1[4], af1k0[4], af1k1[4], bfr0[4], bfr1[4];
    rdA(buf,0,0,af0k0); rdA(buf,0,1,af0k1); rdB(buf,0,bfr0);
    stageH(t+1,2);
    __builtin_amdgcn_s_barrier();
    asm volatile("s_waitcnt lgkmcnt(0)" ::: "memory");
    __builtin_amdgcn_sched_barrier(0);
    __builtin_amdgcn_s_setprio(1);
    #pragma unroll
    for (int mi=0;mi<4;++mi)
      #pragma unroll
      for (int ni=0;ni<4;++ni) MFMA16(af0k0[mi], bfr0[ni], acc[mi][ni]);
    __builtin_amdgcn_s_setprio(0);
    __builtin_amdgcn_sched_barrier(0);
    __builtin_amdgcn_s_barrier();
    rdA(buf,1,0,af1k0); rdA(buf,1,1,af1k1); rdB(buf,1,bfr1);
    stageH(t+1,3);
    __builtin_amdgcn_s_barrier();
    asm volatile("s_waitcnt lgkmcnt(0)" ::: "memory");
    __builtin_amdgcn_sched_barrier(0);
    __builtin_amdgcn_s_setprio(1);
    #pragma unroll
    for (int mi=0;mi<4;++mi)
      #pragma unroll
      for (int ni=0;ni<4;++ni) MFMA16(af1k0[mi], bfr0[ni], acc[4+mi][ni]);
    __builtin_amdgcn_s_setprio(0);
    __builtin_amdgcn_sched_barrier(0);
    __builtin_amdgcn_s_barrier();
    stageH(t+2,0);
    stageH(t+2,1);
    __builtin_amdgcn_s_setprio(1);
    #pragma unroll
    for (int mi=0;mi<4;++mi)
      #pragma unroll
      for (int ni=0;ni<4;++ni) MFMA16(af0k1[mi], bfr1[ni], acc[mi][ni]);
    #pragma unroll
    for (int mi=0;mi<4;++mi)
      #pragma unroll
      for (int ni=0;ni<4;++ni) MFMA16(af1k1[mi], bfr1[ni], acc[4+mi][ni]);
    __builtin_amdgcn_s_setprio(0);
    if (t + 2 < NT) asm volatile("s_waitcnt vmcnt(4)" ::: "memory");
    else            asm volatile("s_waitcnt vmcnt(0)" ::: "memory");
    __builtin_amdgcn_sched_barrier(0);
    __builtin_amdgcn_s_barrier();
  }

  #pragma unroll
  for (int mi=0;mi<8;++mi){
    #pragma unroll
    for (int r=0;r<4;++r){
      size_t row = m0 + wm*128 + mi*16 + 4*lh + r;
      #pragma unroll
      for (int ni=0;ni<4;++ni){
        size_t col = n0 + wn*64 + ni*16 + l15;
        float v = acc[mi][ni][r];
        if (MODE==0) ((bf16*)outp)[row*(size_t)N + col] = (bf16)v;
        else if (MODE==1) ((float*)outp)[row*(size_t)N + col] = v + bias[col] + resid[row*(size_t)N + col];
        else { v += bias[col];
               ((bf16*)outp)[row*(size_t)N + col] =
                   (bf16)(0.5f*v*(1.0f + erff(v*0.70710678f))); }
      }
    }
  }
}

// ---- GEMM 32x128 body (BK=64, 2-phase dbuf, swizzled): As = 2*2048 bf16,
// Bs = 2*8192 bf16 carved from the caller's LDS. M-clamped staging + guarded
// C writes so any M works. mode: 0 = bf16 out, 1 = f32 out + bias + resid.
DEV void g32_body(bf16* As, bf16* Bs, size_t m0, size_t n0,
                  const bf16* __restrict__ A, const bf16* __restrict__ Bt,
                  const float* __restrict__ bias, const float* resid,
                  void* outp, int M, int N, int K, int mode, int tid)
{
  const int lane = tid & 63, wid = tid >> 6;
  const int l15 = lane & 15, lh = lane >> 4;

  f32x4 acc[2][2];
  #pragma unroll
  for (int i=0;i<2;++i)
    #pragma unroll
    for (int j=0;j<2;++j) acc[i][j] = (f32x4){0.f,0.f,0.f,0.f};

  const int srow8 = lane >> 3;
  const int scol  = ((lane & 7) ^ srow8) * 8;
  const int NT = K >> 6;

  auto stage = [&](int t, int buf){
    const int k0 = t << 6;
    {
      int r = wid*8;
      int ar = (int)m0 + r + srow8; if (ar >= M) ar = M - 1;
      gload16(A + (size_t)ar*K + k0 + scol, As + buf*2048 + r*64);
    }
    #pragma unroll
    for (int i = 0; i < 4; ++i) {
      int r = wid*32 + i*8;
      gload16(Bt + (n0 + (size_t)(r + srow8))*K + k0 + scol, Bs + buf*8192 + r*64);
    }
  };

  stage(0, 0);
  __syncthreads();

  for (int t = 0; t < NT; ++t) {
    const int cur = t & 1;
    if (t + 1 < NT) stage(t + 1, cur ^ 1);
    #pragma unroll
    for (int kk = 0; kk < 2; ++kk) {
      bf16x8 af[2], bfr[2];
      #pragma unroll
      for (int i=0;i<2;++i){
        const int arow = i*16 + l15;
        af[i]  = *(const bf16x8*)&As[cur*2048 + arow*64 + (((kk*4+lh) ^ (arow&7))<<3)];
      }
      #pragma unroll
      for (int n=0;n<2;++n){
        const int brow = wid*32 + n*16 + l15;
        bfr[n] = *(const bf16x8*)&Bs[cur*8192 + brow*64 + (((kk*4+lh) ^ (brow&7))<<3)];
      }
      #pragma unroll
      for (int mi=0;mi<2;++mi)
        #pragma unroll
        for (int ni=0;ni<2;++ni)
          MFMA16(af[mi], bfr[ni], acc[mi][ni]);
    }
    __syncthreads();
  }

  #pragma unroll
  for (int mi=0;mi<2;++mi){
    #pragma unroll
    for (int r=0;r<4;++r){
      size_t row = m0 + mi*16 + 4*lh + r;
      if (row < (size_t)M) {
        #pragma unroll
        for (int ni=0;ni<2;++ni){
          size_t col = n0 + wid*32 + ni*16 + l15;
          float v = acc[mi][ni][r];
          if (mode == 0) ((bf16*)outp)[row*(size_t)N + col] = (bf16)v;
          else ((float*)outp)[row*(size_t)N + col] = v + bias[col] + resid[row*(size_t)N + col];
        }
      }
    }
  }
}

// ---- GEMM 32x128 standalone (m-major XCD decode), 4 blocks/CU ----
template<int MODE>
__global__ __launch_bounds__(256) void gemm32(
    const bf16* __restrict__ A, const bf16* __restrict__ Bt,
    const float* __restrict__ bias, const float* resid,
    void* outp, int M, int N, int K)
{
  __shared__ __align__(16) bf16 As[2*32*64];
  __shared__ __align__(16) bf16 Bs[2*128*64];
  const int nwg = gridDim.x * gridDim.y;
  const int lin = blockIdx.y * gridDim.x + blockIdx.x;
  const int wg  = (lin & 7) * (nwg >> 3) + (lin >> 3);
  const size_t m0 = (size_t)(wg / gridDim.x) * 32;
  const size_t n0 = (size_t)(wg % gridDim.x) * 128;
  g32_body(As, Bs, m0, n0, A, Bt, bias, resid, outp, M, N, K, MODE, threadIdx.x);
}

// ---- fused SA proj GEMM (1024 blocks, MODE1) + CA-KV GEMM (80 blocks) ----
// blocks [0,1024): x1 = attn @ wprojSaT^T + bias + x (M=4096,N=1024,K=1024).
// blocks [1024,1104): kvca = condb @ wkvCaT^T (M=154,N=2048,K=768).
__global__ __launch_bounds__(256) void proj_kv(
    const bf16* __restrict__ attn, const bf16* __restrict__ wprojSaT,
    const float* __restrict__ bproj, const float* __restrict__ x, float* x1,
    const bf16* __restrict__ condb, const bf16* __restrict__ wkvCaT, bf16* kvca)
{
  __shared__ __align__(16) bf16 As[2*32*64];
  __shared__ __align__(16) bf16 Bs[2*128*64];
  const int bid = blockIdx.x;
  if (bid < 1024) {
    const int wg  = (bid & 7) * 128 + (bid >> 3);   // m-major swizzle, nwg=1024
    const size_t m0 = (size_t)(wg >> 3) * 32;
    const size_t n0 = (size_t)(wg & 7) * 128;
    g32_body(As, Bs, m0, n0, attn, wprojSaT, bproj, x, x1,
             4096, 1024, 1024, 1, threadIdx.x);
  } else {
    const int g = bid - 1024;                        // 80 blocks: 5 m x 16 n
    const size_t m0 = (size_t)(g / 16) * 32;
    const size_t n0 = (size_t)(g % 16) * 128;
    g32_body(As, Bs, m0, n0, condb, wkvCaT, nullptr, nullptr, kvca,
             154, 2048, 768, 0, threadIdx.x);
  }
}

// ---- V rearrange for SA: vt[bh][d][s] = qkv[b*2048+s][2048 + h*64 + d] ----
__global__ __launch_bounds__(256) void vtsa_kernel(const bf16* __restrict__ qkv, bf16* __restrict__ vt)
{
  __shared__ bf16 t[32][33];
  const int b = blockIdx.z >> 4, h = blockIdx.z & 15;
  const int s0 = blockIdx.x*32, d0 = blockIdx.y*32;
  const int tx = threadIdx.x & 31, ty = threadIdx.x >> 5;
  #pragma unroll
  for (int i = ty; i < 32; i += 8)
    t[i][tx] = qkv[(size_t)(b*2048 + s0+i)*3072 + 2048 + h*64 + d0 + tx];
  __syncthreads();
  #pragma unroll
  for (int i = ty; i < 32; i += 8)
    vt[((size_t)blockIdx.z*64 + d0+i)*2048 + s0 + tx] = t[tx][i];
}

// ---- Flash attention v6: unpaired 1-tile-per-block, 3 blocks/CU ----
template<int CAUSAL>
__global__ __launch_bounds__(256) void flash6(
    const bf16* __restrict__ qb, long q_bstride, long qstride,
    const bf16* __restrict__ kb0, long k_bstride, long k_hstride, long kstride,
    const bf16* __restrict__ vtb, long vt_bhstride, long vtstride,
    bf16* __restrict__ out, int skv)
{
  __shared__ __align__(16) bf16 Ks[2][64*64];
  __shared__ __align__(16) bf16 Vs[2][64*64];
  __shared__ __align__(16) bf16 Ps[4][16*68];
  const int tid = threadIdx.x;
  const int w = tid >> 6, lane = tid & 63, l15 = lane & 15, lh = lane >> 4;
  const int bid = blockIdx.x;
  const int bh   = (bid & 7) + 8*((bid >> 3) & 3);   // bh&7 == bid&7 -> XCD-resident K/V
  const int tile = 31 - (bid >> 5);                  // longest-first dispatch
  const int b = bh >> 4, h = bh & 15;
  const int q0 = tile * 64;
  const int nkb   = CAUSAL ? tile + 1 : ((skv + 63) >> 6);
  const int nfull = CAUSAL ? tile     : (skv >> 6);

  const bf16* kbase = kb0 + (size_t)b*k_bstride + (size_t)h*k_hstride;
  const bf16* vbase = vtb + (size_t)bh*vt_bhstride;
  const int sr0 = tid >> 3, sslot = tid & 7;

  const bf16* qrow = qb + (size_t)b*q_bstride + (size_t)h*64
                        + (size_t)(q0 + w*16 + l15)*qstride;
  bf16x8 qf0 = *(const bf16x8*)(qrow + 8*lh);
  bf16x8 qf1 = *(const bf16x8*)(qrow + 32 + 8*lh);

  f32x4 o[4];
  #pragma unroll
  for (int i=0;i<4;++i) o[i] = (f32x4){0.f,0.f,0.f,0.f};
  float lacc[4] = {0.f,0.f,0.f,0.f};

  bf16x8 kreg[2], vreg[2];
  #pragma unroll
  for (int i=0;i<2;++i){
    int r = sr0 + 32*i;
    kreg[i] = *(const bf16x8*)(kbase + (size_t)r*kstride + sslot*8);
    vreg[i] = *(const bf16x8*)(vbase + (size_t)r*vtstride + sslot*8);
  }

  for (int kb = 0; kb < nkb; ++kb) {
    const int buf = kb & 1;
    #pragma unroll
    for (int i=0;i<2;++i){
      int r = sr0 + 32*i;
      int ps = (sslot ^ (r & 7)) * 8;
      *(bf16x8*)&Ks[buf][r*64 + ps] = kreg[i];
      *(bf16x8*)&Vs[buf][r*64 + ps] = vreg[i];
    }
    __syncthreads();
    if (kb + 1 < nkb) {
      #pragma unroll
      for (int i=0;i<2;++i){
        int r = sr0 + 32*i;
        kreg[i] = *(const bf16x8*)(kbase + (size_t)((kb+1)*64 + r)*kstride + sslot*8);
        vreg[i] = *(const bf16x8*)(vbase + (size_t)r*vtstride + (kb+1)*64 + sslot*8);
      }
    }
    f32x4 sf[4];
    __builtin_amdgcn_s_setprio(1);
    #pragma unroll
    for (int ni = 0; ni < 4; ++ni) {
      int kr = ni*16 + l15;
      bf16x8 kf0 = *(const bf16x8*)&Ks[buf][kr*64 + (((lh  ) ^ (kr&7))<<3)];
      bf16x8 kf1 = *(const bf16x8*)&Ks[buf][kr*64 + (((lh+4) ^ (kr&7))<<3)];
      f32x4 z = (f32x4){0.f,0.f,0.f,0.f};
      MFMA16(qf0, kf0, z);
      MFMA16(qf1, kf1, z);
      sf[ni] = z;
    }
    __builtin_amdgcn_s_setprio(0);
    if (kb >= nfull) {
      #pragma unroll
      for (int ni=0;ni<4;++ni){
        int col = kb*64 + ni*16 + l15;
        #pragma unroll
        for (int r=0;r<4;++r){
          int rowg = q0 + w*16 + 4*lh + r;
          if (col >= skv || (CAUSAL && col > rowg)) sf[ni][r] = -1e30f;
        }
      }
    }
    #pragma unroll
    for (int ni=0;ni<4;++ni){
      #pragma unroll
      for (int r=0;r<4;++r){
        float p = __expf(sf[ni][r]);
        lacc[r] += p;
        Ps[w][(4*lh + r)*68 + ni*16 + l15] = (bf16)p;
      }
    }
    bf16x8 pa0 = *(const bf16x8*)&Ps[w][l15*68 + 8*lh];
    bf16x8 pa1 = *(const bf16x8*)&Ps[w][l15*68 + 32 + 8*lh];
    __builtin_amdgcn_s_setprio(1);
    #pragma unroll
    for (int nd=0;nd<4;++nd){
      int vr = nd*16 + l15;
      bf16x8 vf0 = *(const bf16x8*)&Vs[buf][vr*64 + (((lh  ) ^ (vr&7))<<3)];
      bf16x8 vf1 = *(const bf16x8*)&Vs[buf][vr*64 + (((lh+4) ^ (vr&7))<<3)];
      MFMA16(pa0, vf0, o[nd]);
      MFMA16(pa1, vf1, o[nd]);
    }
    __builtin_amdgcn_s_setprio(0);
  }
  float lr[4];
  #pragma unroll
  for (int r=0;r<4;++r) lr[r] = lacc[r];
  #pragma unroll
  for (int off=1; off<16; off<<=1)
    #pragma unroll
    for (int r=0;r<4;++r) lr[r] += __shfl_xor(lr[r], off);
  #pragma unroll
  for (int nd=0;nd<4;++nd)
    #pragma unroll
    for (int r=0;r<4;++r){
      int rowg = q0 + w*16 + 4*lh + r;
      out[(size_t)(b*2048 + rowg)*1024 + h*64 + nd*16 + l15] =
          (bf16)(o[nd][r] / lr[r]);
    }
}

// ---- host ----
struct Bump { char* base; size_t off;
  void* get(size_t bytes){ void* p = base + off; off += (bytes + 255) & ~(size_t)255; return p; } };

extern "C" void kernel_launch(void* const* d_in, const int* in_sizes, int n_in,
                              void* d_out, int out_size, void* d_ws, size_t ws_size,
                              hipStream_t stream)
{
  const float* x        = (const float*)d_in[0];
  const float* cond     = (const float*)d_in[1];
  const float* Wqkv     = (const float*)d_in[2];
  const float* Wproj_sa = (const float*)d_in[3];
  const float* bproj_sa = (const float*)d_in[4];
  const float* g1       = (const float*)d_in[5];
  const float* b1       = (const float*)d_in[6];
  const float* Wq_ca    = (const float*)d_in[7];
  const float* Wkv_ca   = (const float*)d_in[8];
  const float* Wproj_ca = (const float*)d_in[9];
  const float* bproj_ca = (const float*)d_in[10];
  const float* g2       = (const float*)d_in[11];
  const float* b2       = (const float*)d_in[12];
  const float* Wff1     = (const float*)d_in[13];
  const float* bff1     = (const float*)d_in[14];
  const float* Wff2     = (const float*)d_in[15];
  const float* bff2     = (const float*)d_in[16];
  const float* g3       = (const float*)d_in[17];
  const float* b3       = (const float*)d_in[18];

  Bump bump{(char*)d_ws, 0};
  bf16* wqkvT    = (bf16*)bump.get((size_t)3072*1024*2);
  bf16* wprojSaT = (bf16*)bump.get((size_t)1024*1024*2);
  bf16* wqCaT    = (bf16*)bump.get((size_t)1024*1024*2);
  bf16* wkvCaT   = (bf16*)bump.get((size_t)2048*768*2);
  bf16* wprojCaT = (bf16*)bump.get((size_t)1024*1024*2);
  bf16* wff1T    = (bf16*)bump.get((size_t)4096*1024*2);
  bf16* wff2T    = (bf16*)bump.get((size_t)1024*4096*2);
  bf16* condb    = (bf16*)bump.get((size_t)154*768*2);
  bf16* xn       = (bf16*)bump.get((size_t)4096*1024*2);
  bf16* qkv      = (bf16*)bump.get((size_t)4096*3072*2);   // 25165824 B
  bf16* vt_sa    = (bf16*)bump.get((size_t)2*16*64*2048*2);//  8388608 B (follows qkv)
  bf16* attn     = (bf16*)bump.get((size_t)4096*1024*2);
  bf16* kvca     = (bf16*)bump.get((size_t)154*2048*2);
  bf16* kpad     = (bf16*)bump.get((size_t)2*16*128*64*2);
  bf16* vtca     = (bf16*)bump.get((size_t)2*16*64*128*2);
  bf16* h1   = qkv;             // FF hidden: qkv+vt_sa dead by FF1
  bf16* qca  = vt_sa;           // CA query: vt_sa dead after SA flash
  float* x1  = (float*)d_out;   // residual stream lives in d_out

  // weight prep + LN1 fused in one launch (independent work, runs concurrently)
  prep_ln<<<dim3(8180), 256, 0, stream>>>(
      Wqkv, wqkvT, Wproj_sa, wprojSaT, Wq_ca, wqCaT, Wkv_ca, wkvCaT,
      Wproj_ca, wprojCaT, Wff1, wff1T, Wff2, wff2T, cond, condb,
      x, g1, b1, xn);

  // self-attention (SA proj + CA-KV GEMM fused)
  gemm256p<0><<<dim3(12,16), 512, 0, stream>>>(xn, wqkvT, nullptr, nullptr, qkv, 4096, 3072, 1024);
  vtsa_kernel<<<dim3(64,2,32), 256, 0, stream>>>(qkv, vt_sa);
  flash6<1><<<dim3(1024), 256, 0, stream>>>(
      qkv,        (long)2048*3072, 3072,
      qkv + 1024, (long)2048*3072, 64, 3072,
      vt_sa,      (long)64*2048, 2048,
      attn, 2048);
  proj_kv<<<dim3(1104), 256, 0, stream>>>(attn, wprojSaT, bproj_sa, x, x1,
                                          condb, wkvCaT, kvca);

  // cross-attention (LN2 + kvca_re fused)
  ln_re<<<dim3(5120), 256, 0, stream>>>(x1, g2, b2, xn, kvca, kpad, vtca);
  gemm32<0><<<dim3(8,128), 256, 0, stream>>>(xn, wqCaT, nullptr, nullptr, qca, 4096, 1024, 1024);
  flash6<0><<<dim3(1024), 256, 0, stream>>>(
      qca,  (long)2048*1024, 1024,
      kpad, (long)16*128*64, (long)128*64, 64,
      vtca, (long)64*128, 128,
      attn, 77);
  gemm32<1><<<dim3(8,128), 256, 0, stream>>>(attn, wprojCaT, bproj_ca, x1, x1, 4096, 1024, 1024);

  // FFN
  ln_kernel<<<dim3(4096), 256, 0, stream>>>(x1, g3, b3, xn);
  gemm256p<2><<<dim3(16,16), 512, 0, stream>>>(xn, wff1T, bff1, nullptr, h1, 4096, 4096, 1024);
  gemm32<1><<<dim3(8,128), 256, 0, stream>>>(h1, wff2T, bff2, x1, d_out, 4096, 1024, 4096);

  (void)in_sizes; (void)n_in; (void)out_size; (void)ws_size;
}